// Round 1
// baseline (6724.230 us; speedup 1.0000x reference)
//
#include <hip/hip_runtime.h>
#include <math.h>

// ---------------------------------------------------------------------------
// VQ-VAE forward, fp32, MI355X baseline.
// Layers:
//  1. conv 156->64, 4x4 s2 p1, BN+ReLU    (8,156,128,128)->(8,64,64,64)
//  2. conv 64->128, 4x4 s2 p1, BN+ReLU    ->(8,128,32,32)
//  3. conv 128->128, 3x3 s1 p1            ->(8,128,32,32)
//  4. VQ: argmin_k |z - cb_k|^2 (expanded form), gather e, write idx
//  5. conv 128->128, 3x3 s1 p1, ReLU
//  6. convT 128->64, 4x4 s2 p1, ReLU      ->(8,64,64,64)
//  7. convT 64->156, 4x4 s2 p1, sigmoid   ->(8,156,128,128)
// d_out = [x_hat (20447232) | e (1048576) | idx as float (8192)]
// ---------------------------------------------------------------------------

#define BN_EPS 1e-5f

// MODE: 0 = bias only, 1 = BN+ReLU, 2 = ReLU, 3 = sigmoid
template <int KH, int KW, int S, int P, int MODE>
__global__ __launch_bounds__(256) void conv_k(
    const float* __restrict__ x, const float* __restrict__ w,
    const float* __restrict__ bias,
    const float* __restrict__ bng, const float* __restrict__ bnb,
    const float* __restrict__ bnm, const float* __restrict__ bnv,
    float* __restrict__ y,
    int B, int Cin, int Hin, int Win, int Cout, int Hout, int Wout)
{
    int i = blockIdx.x * 256 + threadIdx.x;
    int total = B * Cout * Hout * Wout;
    if (i >= total) return;
    int ow = i % Wout;
    int t = i / Wout;
    int oh = t % Hout;
    t /= Hout;
    int oc = t % Cout;
    int b = t / Cout;

    int ih0 = oh * S - P;
    int iw0 = ow * S - P;

    float acc = 0.0f;
    for (int ic = 0; ic < Cin; ++ic) {
        const float* xp = x + ((size_t)(b * Cin + ic) * Hin) * Win;
        const float* wp = w + ((size_t)(oc * Cin + ic) * KH) * KW;
#pragma unroll
        for (int kh = 0; kh < KH; ++kh) {
            int ih = ih0 + kh;
            if ((unsigned)ih >= (unsigned)Hin) continue;
#pragma unroll
            for (int kw = 0; kw < KW; ++kw) {
                int iw = iw0 + kw;
                if ((unsigned)iw >= (unsigned)Win) continue;
                acc = fmaf(xp[ih * Win + iw], wp[kh * KW + kw], acc);
            }
        }
    }
    float r = acc + bias[oc];
    if (MODE == 1) {
        float scale = bng[oc] / sqrtf(bnv[oc] + BN_EPS);
        r = r * scale + (bnb[oc] - bnm[oc] * scale);
        r = fmaxf(r, 0.0f);
    } else if (MODE == 2) {
        r = fmaxf(r, 0.0f);
    } else if (MODE == 3) {
        r = 1.0f / (1.0f + expf(-r));
    }
    y[i] = r;
}

// ConvTranspose2d, kernel 4x4, stride 2, pad 1. Torch weight layout (Cin, Cout, 4, 4).
// MODE: 2 = ReLU, 3 = sigmoid
template <int MODE>
__global__ __launch_bounds__(256) void convt_k(
    const float* __restrict__ x, const float* __restrict__ w,
    const float* __restrict__ bias, float* __restrict__ y,
    int B, int Cin, int Hin, int Win, int Cout, int Hout, int Wout)
{
    int i = blockIdx.x * 256 + threadIdx.x;
    int total = B * Cout * Hout * Wout;
    if (i >= total) return;
    int ow = i % Wout;
    int t = i / Wout;
    int oh = t % Hout;
    t /= Hout;
    int oc = t % Cout;
    int b = t / Cout;

    // oh = ih*2 - 1 + kh  ->  ih = (oh + 1 - kh) / 2, kh parity = (oh+1)&1
    int kh0 = (oh + 1) & 1;
    int kw0 = (ow + 1) & 1;
    int ih_a = (oh + 1 - kh0) >> 1;   // tap kh0
    int ih_b = ih_a - 1;              // tap kh0+2
    int iw_a = (ow + 1 - kw0) >> 1;   // tap kw0
    int iw_b = iw_a - 1;              // tap kw0+2
    bool va_h = (ih_a >= 0) && (ih_a < Hin);
    bool vb_h = (ih_b >= 0) && (ih_b < Hin);
    bool va_w = (iw_a >= 0) && (iw_a < Win);
    bool vb_w = (iw_b >= 0) && (iw_b < Win);

    float acc = 0.0f;
    for (int ic = 0; ic < Cin; ++ic) {
        const float* xp = x + ((size_t)(b * Cin + ic) * Hin) * Win;
        const float* wp = w + ((size_t)(ic * Cout + oc)) * 16;
        if (va_h) {
            const float* xr = xp + ih_a * Win;
            if (va_w) acc = fmaf(xr[iw_a], wp[kh0 * 4 + kw0], acc);
            if (vb_w) acc = fmaf(xr[iw_b], wp[kh0 * 4 + kw0 + 2], acc);
        }
        if (vb_h) {
            const float* xr = xp + ih_b * Win;
            if (va_w) acc = fmaf(xr[iw_a], wp[(kh0 + 2) * 4 + kw0], acc);
            if (vb_w) acc = fmaf(xr[iw_b], wp[(kh0 + 2) * 4 + kw0 + 2], acc);
        }
    }
    float r = acc + bias[oc];
    if (MODE == 2) {
        r = fmaxf(r, 0.0f);
    } else if (MODE == 3) {
        r = 1.0f / (1.0f + expf(-r));
    }
    y[i] = r;
}

// Codebook squared norms: cbn[k] = sum_d cb[k][d]^2, K=512, D=128
__global__ __launch_bounds__(256) void cb_norms_k(const float* __restrict__ cb,
                                                  float* __restrict__ cbn)
{
    int k = blockIdx.x * 256 + threadIdx.x;
    if (k >= 512) return;
    const float* cp = cb + (size_t)k * 128;
    float s = 0.0f;
#pragma unroll
    for (int d = 0; d < 128; ++d) s = fmaf(cp[d], cp[d], s);
    cbn[k] = s;
}

// VQ: z (8,128,32,32) NCHW; zf[b,n,d] = z[b,d,n] with n = h*32+w (N=1024).
// dist = |z|^2 - 2 z.cb_k + |cb_k|^2 ; argmin over k (first occurrence on ties).
// e[b,d,n] = cb[idx][d];  idxf[b*1024+n] = (float)idx.
// Block: 256 threads = 64 n-rows x 4 k-quarters. Grid: 8*16 = 128 blocks.
__global__ __launch_bounds__(256) void vq_k(
    const float* __restrict__ z, const float* __restrict__ cb,
    const float* __restrict__ cbn,
    float* __restrict__ e, float* __restrict__ idxf)
{
    int blk = blockIdx.x;
    int b = blk >> 4;
    int n0 = (blk & 15) << 6;
    int t = threadIdx.x;
    int nl = t & 63;
    int kq = t >> 6;
    int n = n0 + nl;

    // load z row into registers (coalesced across the 64 lanes of each wave)
    float zr[128];
#pragma unroll
    for (int d = 0; d < 128; ++d) zr[d] = z[(size_t)(b * 128 + d) * 1024 + n];
    float zn = 0.0f;
#pragma unroll
    for (int d = 0; d < 128; ++d) zn = fmaf(zr[d], zr[d], zn);

    float best = 3.4e38f;
    int bk = kq * 128;
    for (int k = kq * 128; k < kq * 128 + 128; ++k) {
        const float* cp = cb + (size_t)k * 128;
        float dot = 0.0f;
#pragma unroll
        for (int d = 0; d < 128; ++d) dot = fmaf(zr[d], cp[d], dot);
        float dist = (zn - 2.0f * dot) + cbn[k];
        if (dist < best) { best = dist; bk = k; }  // strict <: first-min wins
    }

    __shared__ float sd[256];
    __shared__ int si[256];
    sd[t] = best;
    si[t] = bk;
    __syncthreads();
    if (kq == 0) {
        // quarters are ascending k-ranges; strict < keeps the lowest-k winner
        for (int q = 1; q < 4; ++q) {
            float d2 = sd[t + q * 64];
            int k2 = si[t + q * 64];
            if (d2 < best || (d2 == best && k2 < bk)) { best = d2; bk = k2; }
        }
        si[t] = bk;  // slot nl holds the final index
        idxf[b * 1024 + n] = (float)bk;
    }
    __syncthreads();

    // gather e: 64 n x 128 d = 8192 values, 32 per thread, coalesced along n
    for (int r = 0; r < 32; ++r) {
        int lin = t + r * 256;
        int d = lin >> 6;
        int nn = lin & 63;
        int kidx = si[nn];
        e[(size_t)(b * 128 + d) * 1024 + n0 + nn] = cb[(size_t)kidx * 128 + d];
    }
}

extern "C" void kernel_launch(void* const* d_in, const int* in_sizes, int n_in,
                              void* d_out, int out_size, void* d_ws, size_t ws_size,
                              hipStream_t stream)
{
    const float* x      = (const float*)d_in[0];
    const float* enc_w1 = (const float*)d_in[1];
    const float* enc_b1 = (const float*)d_in[2];
    const float* bn1_g  = (const float*)d_in[3];
    const float* bn1_b  = (const float*)d_in[4];
    const float* bn1_m  = (const float*)d_in[5];
    const float* bn1_v  = (const float*)d_in[6];
    const float* enc_w2 = (const float*)d_in[7];
    const float* enc_b2 = (const float*)d_in[8];
    const float* bn2_g  = (const float*)d_in[9];
    const float* bn2_b  = (const float*)d_in[10];
    const float* bn2_m  = (const float*)d_in[11];
    const float* bn2_v  = (const float*)d_in[12];
    const float* enc_w3 = (const float*)d_in[13];
    const float* enc_b3 = (const float*)d_in[14];
    const float* cb     = (const float*)d_in[15];
    const float* dec_w1 = (const float*)d_in[16];
    const float* dec_b1 = (const float*)d_in[17];
    const float* dec_w2 = (const float*)d_in[18];
    const float* dec_b2 = (const float*)d_in[19];
    const float* dec_w3 = (const float*)d_in[20];
    const float* dec_b3 = (const float*)d_in[21];

    float* ws = (float*)d_ws;
    float* z1  = ws;                  // (8,64,64,64)   2097152
    float* z2  = z1 + 2097152;        // (8,128,32,32)  1048576
    float* z3  = z2 + 1048576;        // (8,128,32,32)  1048576
    float* cbn = z3 + 1048576;        // (512)
    float* h1  = cbn + 512;           // (8,128,32,32)  1048576
    float* h2  = h1 + 1048576;        // (8,64,64,64)   2097152

    float* out   = (float*)d_out;
    float* x_hat = out;               // 20447232
    float* e     = out + 20447232;    // 1048576
    float* idxf  = e + 1048576;       // 8192

    // 1. conv1 + BN + ReLU
    conv_k<4, 4, 2, 1, 1><<<8192, 256, 0, stream>>>(
        x, enc_w1, enc_b1, bn1_g, bn1_b, bn1_m, bn1_v, z1,
        8, 156, 128, 128, 64, 64, 64);
    // 2. conv2 + BN + ReLU
    conv_k<4, 4, 2, 1, 1><<<4096, 256, 0, stream>>>(
        z1, enc_w2, enc_b2, bn2_g, bn2_b, bn2_m, bn2_v, z2,
        8, 64, 64, 64, 128, 32, 32);
    // 3. conv3 (bias only)
    conv_k<3, 3, 1, 1, 0><<<4096, 256, 0, stream>>>(
        z2, enc_w3, enc_b3, nullptr, nullptr, nullptr, nullptr, z3,
        8, 128, 32, 32, 128, 32, 32);
    // 4. VQ
    cb_norms_k<<<2, 256, 0, stream>>>(cb, cbn);
    vq_k<<<128, 256, 0, stream>>>(z3, cb, cbn, e, idxf);
    // 5. dec conv1 + ReLU (reads e from d_out)
    conv_k<3, 3, 1, 1, 2><<<4096, 256, 0, stream>>>(
        e, dec_w1, dec_b1, nullptr, nullptr, nullptr, nullptr, h1,
        8, 128, 32, 32, 128, 32, 32);
    // 6. dec convT2 + ReLU
    convt_k<2><<<8192, 256, 0, stream>>>(
        h1, dec_w2, dec_b2, h2,
        8, 128, 32, 32, 64, 64, 64);
    // 7. dec convT3 + sigmoid
    convt_k<3><<<79872, 256, 0, stream>>>(
        h2, dec_w3, dec_b3, x_hat,
        8, 64, 64, 64, 156, 128, 128);
}

// Round 2
// 1427.081 us; speedup vs baseline: 4.7119x; 4.7119x over previous
//
#include <hip/hip_runtime.h>
#include <math.h>

#define BN_EPS 1e-5f

__device__ __forceinline__ float sigmoidf_(float v) { return 1.0f / (1.0f + expf(-v)); }

// ---------------------------------------------------------------------------
// conv1: 156->64, 4x4 s2 p1, BN+ReLU. in (8,156,128,128) -> out (8,64,64,64)
// Block: one (b, oh) row: 64 oc x 64 ow. 256 thr = 16 ocg x 16 owg, 4oc x 4ow each.
// LDS: weights [64 k][68] (k = icl*16+kh*4+kw), input [4ic][4row][2 parity][66].
// ---------------------------------------------------------------------------
__global__ __launch_bounds__(256) void conv1_k(
    const float* __restrict__ x, const float* __restrict__ wg,
    const float* __restrict__ bias,
    const float* __restrict__ bng, const float* __restrict__ bnb,
    const float* __restrict__ bnm, const float* __restrict__ bnv,
    float* __restrict__ y)
{
    __shared__ float sW[64 * 68];
    __shared__ float sX[4][4][2][66];
    const int blk = blockIdx.x;
    const int b = blk >> 6, oh = blk & 63;
    const int t = threadIdx.x;
    const int ocg = t & 15, owg = t >> 4;
    const int oc0 = ocg * 4, ow0 = owg * 4;
    const int ih0 = oh * 2 - 1;

    float acc[4][4] = {};
    const int kq = t & 63, wq = t >> 6;

    for (int ic0 = 0; ic0 < 156; ic0 += 4) {
        // stage weights: global w[oc][ic][4][4] -> LDS [k][oc], b128 writes
#pragma unroll
        for (int r = 0; r < 4; ++r) {
            int q4 = wq + r * 4;                       // oc-quad 0..15
            int gb = (q4 * 4) * 2496 + ic0 * 16 + kq;  // 2496 = 156*16
            float4 v;
            v.x = wg[gb]; v.y = wg[gb + 2496]; v.z = wg[gb + 4992]; v.w = wg[gb + 7488];
            *(float4*)&sW[kq * 68 + q4 * 4] = v;
        }
        // stage input: 4 ic x 4 rows x iw in [-1,128], parity-split columns
        for (int li = t; li < 2080; li += 256) {
            int q = li % 130;
            int tmp = li / 130;
            int r = tmp & 3, icl = tmp >> 2;
            int iw = q - 1, ih = ih0 + r;
            float v = 0.0f;
            if ((unsigned)ih < 128u && (unsigned)iw < 128u)
                v = x[((size_t)(b * 156 + ic0 + icl) * 128 + ih) * 128 + iw];
            sX[icl][r][(iw & 1) ? 0 : 1][(iw + 1) >> 1] = v;
        }
        __syncthreads();
#pragma unroll
        for (int icl = 0; icl < 4; ++icl) {
#pragma unroll
            for (int kh = 0; kh < 4; ++kh) {
                float x0[5], x1[5];
#pragma unroll
                for (int q = 0; q < 5; ++q) {
                    x0[q] = sX[icl][kh][0][ow0 + q];   // odd iw  -> kw 0,2
                    x1[q] = sX[icl][kh][1][ow0 + q];   // even iw -> kw 1,3
                }
                const int kb = (icl * 16 + kh * 4) * 68 + oc0;
                float w0[4], w1[4], w2[4], w3[4];
                *(float4*)w0 = *(const float4*)&sW[kb];
                *(float4*)w1 = *(const float4*)&sW[kb + 68];
                *(float4*)w2 = *(const float4*)&sW[kb + 136];
                *(float4*)w3 = *(const float4*)&sW[kb + 204];
#pragma unroll
                for (int i = 0; i < 4; ++i)
#pragma unroll
                    for (int m = 0; m < 4; ++m) {
                        acc[i][m] = fmaf(w0[i], x0[m],     acc[i][m]);
                        acc[i][m] = fmaf(w1[i], x1[m],     acc[i][m]);
                        acc[i][m] = fmaf(w2[i], x0[m + 1], acc[i][m]);
                        acc[i][m] = fmaf(w3[i], x1[m + 1], acc[i][m]);
                    }
            }
        }
        __syncthreads();
    }
#pragma unroll
    for (int i = 0; i < 4; ++i) {
        int oc = oc0 + i;
        float s = bng[oc] / sqrtf(bnv[oc] + BN_EPS);
        float o = fmaf(bias[oc], s, bnb[oc] - bnm[oc] * s);
        float4 vv;
        vv.x = fmaxf(fmaf(acc[i][0], s, o), 0.0f);
        vv.y = fmaxf(fmaf(acc[i][1], s, o), 0.0f);
        vv.z = fmaxf(fmaf(acc[i][2], s, o), 0.0f);
        vv.w = fmaxf(fmaf(acc[i][3], s, o), 0.0f);
        *(float4*)&y[((size_t)(b * 64 + oc) * 64 + oh) * 64 + ow0] = vv;
    }
}

// ---------------------------------------------------------------------------
// conv2: 64->128, 4x4 s2 p1, BN+ReLU. in (8,64,64,64) -> out (8,128,32,32)
// Block: one (b, oh): 128 oc x 32 ow. 256 thr = 32 ocg x 8 owg, 4oc x 4ow each.
// ---------------------------------------------------------------------------
__global__ __launch_bounds__(256) void conv2_k(
    const float* __restrict__ x, const float* __restrict__ wg,
    const float* __restrict__ bias,
    const float* __restrict__ bng, const float* __restrict__ bnb,
    const float* __restrict__ bnm, const float* __restrict__ bnv,
    float* __restrict__ y)
{
    __shared__ float sW[64 * 132];
    __shared__ float sX[4][4][2][34];
    const int blk = blockIdx.x;
    const int b = blk >> 5, oh = blk & 31;
    const int t = threadIdx.x;
    const int ocg = t & 31, owg = t >> 5;
    const int oc0 = ocg * 4, ow0 = owg * 4;
    const int ih0 = oh * 2 - 1;

    float acc[4][4] = {};
    const int kq = t & 63, wq = t >> 6;

    for (int ic0 = 0; ic0 < 64; ic0 += 4) {
#pragma unroll
        for (int r = 0; r < 8; ++r) {
            int q4 = wq + r * 4;                      // oc-quad 0..31
            int gb = (q4 * 4) * 1024 + ic0 * 16 + kq; // 1024 = 64*16
            float4 v;
            v.x = wg[gb]; v.y = wg[gb + 1024]; v.z = wg[gb + 2048]; v.w = wg[gb + 3072];
            *(float4*)&sW[kq * 132 + q4 * 4] = v;
        }
        for (int li = t; li < 1056; li += 256) {      // 4*4*66
            int q = li % 66;
            int tmp = li / 66;
            int r = tmp & 3, icl = tmp >> 2;
            int iw = q - 1, ih = ih0 + r;
            float v = 0.0f;
            if ((unsigned)ih < 64u && (unsigned)iw < 64u)
                v = x[((size_t)(b * 64 + ic0 + icl) * 64 + ih) * 64 + iw];
            sX[icl][r][(iw & 1) ? 0 : 1][(iw + 1) >> 1] = v;
        }
        __syncthreads();
#pragma unroll
        for (int icl = 0; icl < 4; ++icl) {
#pragma unroll
            for (int kh = 0; kh < 4; ++kh) {
                float x0[5], x1[5];
#pragma unroll
                for (int q = 0; q < 5; ++q) {
                    x0[q] = sX[icl][kh][0][ow0 + q];
                    x1[q] = sX[icl][kh][1][ow0 + q];
                }
                const int kb = (icl * 16 + kh * 4) * 132 + oc0;
                float w0[4], w1[4], w2[4], w3[4];
                *(float4*)w0 = *(const float4*)&sW[kb];
                *(float4*)w1 = *(const float4*)&sW[kb + 132];
                *(float4*)w2 = *(const float4*)&sW[kb + 264];
                *(float4*)w3 = *(const float4*)&sW[kb + 396];
#pragma unroll
                for (int i = 0; i < 4; ++i)
#pragma unroll
                    for (int m = 0; m < 4; ++m) {
                        acc[i][m] = fmaf(w0[i], x0[m],     acc[i][m]);
                        acc[i][m] = fmaf(w1[i], x1[m],     acc[i][m]);
                        acc[i][m] = fmaf(w2[i], x0[m + 1], acc[i][m]);
                        acc[i][m] = fmaf(w3[i], x1[m + 1], acc[i][m]);
                    }
            }
        }
        __syncthreads();
    }
#pragma unroll
    for (int i = 0; i < 4; ++i) {
        int oc = oc0 + i;
        float s = bng[oc] / sqrtf(bnv[oc] + BN_EPS);
        float o = fmaf(bias[oc], s, bnb[oc] - bnm[oc] * s);
        float4 vv;
        vv.x = fmaxf(fmaf(acc[i][0], s, o), 0.0f);
        vv.y = fmaxf(fmaf(acc[i][1], s, o), 0.0f);
        vv.z = fmaxf(fmaf(acc[i][2], s, o), 0.0f);
        vv.w = fmaxf(fmaf(acc[i][3], s, o), 0.0f);
        *(float4*)&y[((size_t)(b * 128 + oc) * 32 + oh) * 32 + ow0] = vv;
    }
}

// ---------------------------------------------------------------------------
// conv3s1: 128->128, 3x3 s1 p1 on 32x32. MODE 0=bias only, 2=ReLU.
// Block: one (b, oh): 128 oc x 32 ow. 256 thr = 32 ocg x 8 owg.
// ---------------------------------------------------------------------------
template <int MODE>
__global__ __launch_bounds__(256) void conv3s1_k(
    const float* __restrict__ x, const float* __restrict__ wg,
    const float* __restrict__ bias, float* __restrict__ y)
{
    __shared__ float sW[36 * 132];
    __shared__ float sX[4][3][36];
    const int blk = blockIdx.x;
    const int b = blk >> 5, oh = blk & 31;
    const int t = threadIdx.x;
    const int ocg = t & 31, owg = t >> 5;
    const int oc0 = ocg * 4, ow0 = owg * 4;
    const int ih0 = oh - 1;

    float acc[4][4] = {};

    for (int ic0 = 0; ic0 < 128; ic0 += 4) {
        // weights: global w[oc][ic][3][3], runs of 36 per oc for this chunk
        for (int task = t; task < 1152; task += 256) {
            int k = task % 36;
            int qq = task / 36;                       // oc-quad 0..31
            int gb = (qq * 4) * 1152 + ic0 * 9 + k;   // 1152 = 128*9
            float4 v;
            v.x = wg[gb]; v.y = wg[gb + 1152]; v.z = wg[gb + 2304]; v.w = wg[gb + 3456];
            *(float4*)&sW[k * 132 + qq * 4] = v;
        }
        for (int li = t; li < 408; li += 256) {       // 4*3*34
            int q = li % 34;
            int tmp = li / 34;
            int r = tmp % 3, icl = tmp / 3;
            int iw = q - 1, ih = ih0 + r;
            float v = 0.0f;
            if ((unsigned)ih < 32u && (unsigned)iw < 32u)
                v = x[((size_t)(b * 128 + ic0 + icl) * 32 + ih) * 32 + iw];
            sX[icl][r][q] = v;
        }
        __syncthreads();
#pragma unroll
        for (int icl = 0; icl < 4; ++icl) {
#pragma unroll
            for (int kh = 0; kh < 3; ++kh) {
                float xv[6];
#pragma unroll
                for (int q = 0; q < 6; ++q) xv[q] = sX[icl][kh][ow0 + q];
                const int kb = (icl * 9 + kh * 3) * 132 + oc0;
                float w0[4], w1[4], w2[4];
                *(float4*)w0 = *(const float4*)&sW[kb];
                *(float4*)w1 = *(const float4*)&sW[kb + 132];
                *(float4*)w2 = *(const float4*)&sW[kb + 264];
#pragma unroll
                for (int i = 0; i < 4; ++i)
#pragma unroll
                    for (int m = 0; m < 4; ++m) {
                        acc[i][m] = fmaf(w0[i], xv[m],     acc[i][m]);
                        acc[i][m] = fmaf(w1[i], xv[m + 1], acc[i][m]);
                        acc[i][m] = fmaf(w2[i], xv[m + 2], acc[i][m]);
                    }
            }
        }
        __syncthreads();
    }
#pragma unroll
    for (int i = 0; i < 4; ++i) {
        int oc = oc0 + i;
        float bz = bias[oc];
        float4 vv;
        float r0 = acc[i][0] + bz, r1 = acc[i][1] + bz, r2 = acc[i][2] + bz, r3 = acc[i][3] + bz;
        if (MODE == 2) { r0 = fmaxf(r0, 0.f); r1 = fmaxf(r1, 0.f); r2 = fmaxf(r2, 0.f); r3 = fmaxf(r3, 0.f); }
        vv.x = r0; vv.y = r1; vv.z = r2; vv.w = r3;
        *(float4*)&y[((size_t)(b * 128 + oc) * 32 + oh) * 32 + ow0] = vv;
    }
}

// ---------------------------------------------------------------------------
// decT2: convT 128->64, 4x4 s2 p1, ReLU. in (8,128,32,32) -> (8,64,64,64)
// Parity decomposition: per output row oh, kh parity fixed (kh0=(oh+1)&1),
// rows ih_b=ih_a-1 (taps kh0+2), ih_a (taps kh0). Per ow: kw0=(ow+1)&1.
// Block: one (b,oh): 64 oc x 64 ow. 256 thr = 16 ocg x 16 owg, 4oc x 4ow.
// ---------------------------------------------------------------------------
__global__ __launch_bounds__(256) void decT2_k(
    const float* __restrict__ x, const float* __restrict__ wg,
    const float* __restrict__ bias, float* __restrict__ y)
{
    __shared__ float sW[64 * 68];
    __shared__ float sX[4][2][36];
    const int blk = blockIdx.x;
    const int b = blk >> 6, oh = blk & 63;
    const int t = threadIdx.x;
    const int ocg = t & 15, owg = t >> 4;
    const int oc0 = ocg * 4, ow0 = owg * 4;
    const int kh0 = (oh + 1) & 1;
    const int ih_a = (oh + 1 - kh0) >> 1;
    const int ih_b = ih_a - 1;

    float acc[4][4] = {};

    for (int ic0 = 0; ic0 < 128; ic0 += 4) {
        // weights: global (Cin=128, Cout=64, 4, 4) -> LDS [icl*16+tap][oc]
        for (int r = 0; r < 16; ++r) {
            int li = t + 256 * r;                     // 0..4095
            int tap = li & 15, oc = (li >> 4) & 63, icl = li >> 10;
            sW[(icl * 16 + tap) * 68 + oc] = wg[(size_t)(ic0 + icl) * 1024 + oc * 16 + tap];
        }
        for (int li = t; li < 272; li += 256) {       // 4*2*34, idx = iw+1 in [0,33]
            int q = li % 34;
            int tmp = li / 34;
            int r = tmp & 1, icl = tmp >> 1;
            int iw = q - 1, ih = ih_b + r;
            float v = 0.0f;
            if ((unsigned)ih < 32u && (unsigned)iw < 32u)
                v = x[((size_t)(b * 128 + ic0 + icl) * 32 + ih) * 32 + iw];
            sX[icl][r][q] = v;
        }
        __syncthreads();
#pragma unroll
        for (int icl = 0; icl < 4; ++icl) {
            float x0v[4], x1v[4];                     // row ih_b, row ih_a
            const int ib = ow0 >> 1;                  // idx of iw = ow0/2 - 1
#pragma unroll
            for (int q = 0; q < 4; ++q) { x0v[q] = sX[icl][0][ib + q]; x1v[q] = sX[icl][1][ib + q]; }
            const int kbA = (icl * 16 + kh0 * 4) * 68 + oc0;
            const int kbB = kbA + 8 * 68;             // kh0+2
            float wA0[4], wA1[4], wA2[4], wA3[4], wB0[4], wB1[4], wB2[4], wB3[4];
            *(float4*)wA0 = *(const float4*)&sW[kbA];
            *(float4*)wA1 = *(const float4*)&sW[kbA + 68];
            *(float4*)wA2 = *(const float4*)&sW[kbA + 136];
            *(float4*)wA3 = *(const float4*)&sW[kbA + 204];
            *(float4*)wB0 = *(const float4*)&sW[kbB];
            *(float4*)wB1 = *(const float4*)&sW[kbB + 68];
            *(float4*)wB2 = *(const float4*)&sW[kbB + 136];
            *(float4*)wB3 = *(const float4*)&sW[kbB + 204];
#pragma unroll
            for (int i = 0; i < 4; ++i) {
                // m=0 (kw0=1): a=1,b=0 ; m=1 (kw0=0): a=2,b=1
                // m=2 (kw0=1): a=2,b=1 ; m=3 (kw0=0): a=3,b=2
                acc[i][0] = fmaf(wA1[i], x1v[1], acc[i][0]);
                acc[i][0] = fmaf(wA3[i], x1v[0], acc[i][0]);
                acc[i][0] = fmaf(wB1[i], x0v[1], acc[i][0]);
                acc[i][0] = fmaf(wB3[i], x0v[0], acc[i][0]);
                acc[i][1] = fmaf(wA0[i], x1v[2], acc[i][1]);
                acc[i][1] = fmaf(wA2[i], x1v[1], acc[i][1]);
                acc[i][1] = fmaf(wB0[i], x0v[2], acc[i][1]);
                acc[i][1] = fmaf(wB2[i], x0v[1], acc[i][1]);
                acc[i][2] = fmaf(wA1[i], x1v[2], acc[i][2]);
                acc[i][2] = fmaf(wA3[i], x1v[1], acc[i][2]);
                acc[i][2] = fmaf(wB1[i], x0v[2], acc[i][2]);
                acc[i][2] = fmaf(wB3[i], x0v[1], acc[i][2]);
                acc[i][3] = fmaf(wA0[i], x1v[3], acc[i][3]);
                acc[i][3] = fmaf(wA2[i], x1v[2], acc[i][3]);
                acc[i][3] = fmaf(wB0[i], x0v[3], acc[i][3]);
                acc[i][3] = fmaf(wB2[i], x0v[2], acc[i][3]);
            }
        }
        __syncthreads();
    }
#pragma unroll
    for (int i = 0; i < 4; ++i) {
        int oc = oc0 + i;
        float bz = bias[oc];
        float4 vv;
        vv.x = fmaxf(acc[i][0] + bz, 0.f);
        vv.y = fmaxf(acc[i][1] + bz, 0.f);
        vv.z = fmaxf(acc[i][2] + bz, 0.f);
        vv.w = fmaxf(acc[i][3] + bz, 0.f);
        *(float4*)&y[((size_t)(b * 64 + oc) * 64 + oh) * 64 + ow0] = vv;
    }
}

// ---------------------------------------------------------------------------
// decT3: convT 64->156, 4x4 s2 p1, sigmoid. in (8,64,64,64) -> (8,156,128,128)
// Block: (b, oh, octile): 64-oc tile x 128 ow. 256 thr = 16 ocg x 16 owg, 4oc x 8ow.
// ---------------------------------------------------------------------------
__global__ __launch_bounds__(256) void decT3_k(
    const float* __restrict__ x, const float* __restrict__ wg,
    const float* __restrict__ bias, float* __restrict__ y)
{
    __shared__ float sW[64 * 68];
    __shared__ float sX[4][2][68];
    const int blk = blockIdx.x;
    const int octile = blk % 3;
    const int oh = (blk / 3) & 127;
    const int b = blk / 384;
    const int oc_base = octile * 64;
    const int t = threadIdx.x;
    const int ocg = t & 15, owg = t >> 4;
    const int occ = ocg * 4;                          // LDS column base
    const int ow0 = owg * 8;
    const int kh0 = (oh + 1) & 1;
    const int ih_a = (oh + 1 - kh0) >> 1;
    const int ih_b = ih_a - 1;

    float acc[4][8] = {};

    for (int ic0 = 0; ic0 < 64; ic0 += 4) {
        for (int r = 0; r < 16; ++r) {
            int li = t + 256 * r;
            int tap = li & 15, ocp = (li >> 4) & 63, icl = li >> 10;
            int oc_g = oc_base + ocp;
            float v = (oc_g < 156) ? wg[(size_t)(ic0 + icl) * 2496 + oc_g * 16 + tap] : 0.0f;
            sW[(icl * 16 + tap) * 68 + ocp] = v;      // 2496 = 156*16
        }
        for (int li = t; li < 528; li += 256) {       // 4*2*66, idx = iw+1 in [0,65]
            int q = li % 66;
            int tmp = li / 66;
            int r = tmp & 1, icl = tmp >> 1;
            int iw = q - 1, ih = ih_b + r;
            float v = 0.0f;
            if ((unsigned)ih < 64u && (unsigned)iw < 64u)
                v = x[((size_t)(b * 64 + ic0 + icl) * 64 + ih) * 64 + iw];
            sX[icl][r][q] = v;
        }
        __syncthreads();
#pragma unroll
        for (int icl = 0; icl < 4; ++icl) {
            float x0v[6], x1v[6];
            const int ib = ow0 >> 1;
#pragma unroll
            for (int q = 0; q < 6; ++q) { x0v[q] = sX[icl][0][ib + q]; x1v[q] = sX[icl][1][ib + q]; }
            const int kbA = (icl * 16 + kh0 * 4) * 68 + occ;
            const int kbB = kbA + 8 * 68;
            float wA0[4], wA1[4], wA2[4], wA3[4], wB0[4], wB1[4], wB2[4], wB3[4];
            *(float4*)wA0 = *(const float4*)&sW[kbA];
            *(float4*)wA1 = *(const float4*)&sW[kbA + 68];
            *(float4*)wA2 = *(const float4*)&sW[kbA + 136];
            *(float4*)wA3 = *(const float4*)&sW[kbA + 204];
            *(float4*)wB0 = *(const float4*)&sW[kbB];
            *(float4*)wB1 = *(const float4*)&sW[kbB + 68];
            *(float4*)wB2 = *(const float4*)&sW[kbB + 136];
            *(float4*)wB3 = *(const float4*)&sW[kbB + 204];
#pragma unroll
            for (int m = 0; m < 8; ++m) {
                const int a = (m & 1) ? ((m + 1) / 2 + 1) : (m / 2 + 1);
                const int bo = a - 1;
#pragma unroll
                for (int i = 0; i < 4; ++i) {
                    if (m & 1) {                      // kw0 = 0 -> taps kw 0,2
                        acc[i][m] = fmaf(wA0[i], x1v[a],  acc[i][m]);
                        acc[i][m] = fmaf(wA2[i], x1v[bo], acc[i][m]);
                        acc[i][m] = fmaf(wB0[i], x0v[a],  acc[i][m]);
                        acc[i][m] = fmaf(wB2[i], x0v[bo], acc[i][m]);
                    } else {                          // kw0 = 1 -> taps kw 1,3
                        acc[i][m] = fmaf(wA1[i], x1v[a],  acc[i][m]);
                        acc[i][m] = fmaf(wA3[i], x1v[bo], acc[i][m]);
                        acc[i][m] = fmaf(wB1[i], x0v[a],  acc[i][m]);
                        acc[i][m] = fmaf(wB3[i], x0v[bo], acc[i][m]);
                    }
                }
            }
        }
        __syncthreads();
    }
#pragma unroll
    for (int i = 0; i < 4; ++i) {
        int oc = oc_base + occ + i;
        if (oc >= 156) continue;
        float bz = bias[oc];
        float* yp = &y[((size_t)(b * 156 + oc) * 128 + oh) * 128 + ow0];
        float4 v0, v1;
        v0.x = sigmoidf_(acc[i][0] + bz); v0.y = sigmoidf_(acc[i][1] + bz);
        v0.z = sigmoidf_(acc[i][2] + bz); v0.w = sigmoidf_(acc[i][3] + bz);
        v1.x = sigmoidf_(acc[i][4] + bz); v1.y = sigmoidf_(acc[i][5] + bz);
        v1.z = sigmoidf_(acc[i][6] + bz); v1.w = sigmoidf_(acc[i][7] + bz);
        *(float4*)yp = v0;
        *(float4*)(yp + 4) = v1;
    }
}

// ---------------------------------------------------------------------------
// VQ. Same numerics/order as the passed baseline: dist = (zn - 2*dot) + cbn[k],
// sequential fmaf over d. Block: 32 n x 8 k-octants (64 k each). Grid 256.
// ---------------------------------------------------------------------------
__global__ __launch_bounds__(256) void cb_norms_k(const float* __restrict__ cb,
                                                  float* __restrict__ cbn)
{
    int k = blockIdx.x * 256 + threadIdx.x;
    if (k >= 512) return;
    const float* cp = cb + (size_t)k * 128;
    float s = 0.0f;
#pragma unroll
    for (int d = 0; d < 128; ++d) s = fmaf(cp[d], cp[d], s);
    cbn[k] = s;
}

__global__ __launch_bounds__(256) void vq_k(
    const float* __restrict__ z, const float* __restrict__ cb,
    const float* __restrict__ cbn,
    float* __restrict__ e, float* __restrict__ idxf)
{
    const int blk = blockIdx.x;
    const int b = blk >> 5;
    const int n0 = (blk & 31) << 5;
    const int t = threadIdx.x;
    const int nl = t & 31, kq = t >> 5;
    const int n = n0 + nl;

    float zr[128];
#pragma unroll
    for (int d = 0; d < 128; ++d) zr[d] = z[(size_t)(b * 128 + d) * 1024 + n];
    float zn = 0.0f;
#pragma unroll
    for (int d = 0; d < 128; ++d) zn = fmaf(zr[d], zr[d], zn);

    float best = 3.4e38f;
    int bk = kq * 64;
    for (int k = kq * 64; k < kq * 64 + 64; ++k) {
        const float4* cp = (const float4*)(cb + (size_t)k * 128);
        float dot = 0.0f;
#pragma unroll
        for (int j = 0; j < 32; ++j) {
            float4 c = cp[j];
            dot = fmaf(zr[4 * j + 0], c.x, dot);
            dot = fmaf(zr[4 * j + 1], c.y, dot);
            dot = fmaf(zr[4 * j + 2], c.z, dot);
            dot = fmaf(zr[4 * j + 3], c.w, dot);
        }
        float dist = (zn - 2.0f * dot) + cbn[k];
        if (dist < best) { best = dist; bk = k; }     // ascending k: first-min wins
    }
    __shared__ float sd[8][32];
    __shared__ int si[8][32];
    sd[kq][nl] = best;
    si[kq][nl] = bk;
    __syncthreads();
    if (t < 32) {                                     // kq == 0 threads
#pragma unroll
        for (int q = 1; q < 8; ++q) {
            float d2 = sd[q][nl];
            if (d2 < best) { best = d2; bk = si[q][nl]; }
        }
        si[0][nl] = bk;
        idxf[b * 1024 + n] = (float)bk;
    }
    __syncthreads();
    for (int li = t; li < 4096; li += 256) {
        int d = li >> 5, nn = li & 31;
        e[(size_t)(b * 128 + d) * 1024 + n0 + nn] = cb[(size_t)si[0][nn] * 128 + d];
    }
}

// ---------------------------------------------------------------------------
extern "C" void kernel_launch(void* const* d_in, const int* in_sizes, int n_in,
                              void* d_out, int out_size, void* d_ws, size_t ws_size,
                              hipStream_t stream)
{
    const float* x      = (const float*)d_in[0];
    const float* enc_w1 = (const float*)d_in[1];
    const float* enc_b1 = (const float*)d_in[2];
    const float* bn1_g  = (const float*)d_in[3];
    const float* bn1_b  = (const float*)d_in[4];
    const float* bn1_m  = (const float*)d_in[5];
    const float* bn1_v  = (const float*)d_in[6];
    const float* enc_w2 = (const float*)d_in[7];
    const float* enc_b2 = (const float*)d_in[8];
    const float* bn2_g  = (const float*)d_in[9];
    const float* bn2_b  = (const float*)d_in[10];
    const float* bn2_m  = (const float*)d_in[11];
    const float* bn2_v  = (const float*)d_in[12];
    const float* enc_w3 = (const float*)d_in[13];
    const float* enc_b3 = (const float*)d_in[14];
    const float* cb     = (const float*)d_in[15];
    const float* dec_w1 = (const float*)d_in[16];
    const float* dec_b1 = (const float*)d_in[17];
    const float* dec_w2 = (const float*)d_in[18];
    const float* dec_b2 = (const float*)d_in[19];
    const float* dec_w3 = (const float*)d_in[20];
    const float* dec_b3 = (const float*)d_in[21];

    float* ws = (float*)d_ws;
    float* z1  = ws;                  // (8,64,64,64)   2097152
    float* z2  = z1 + 2097152;        // (8,128,32,32)  1048576
    float* z3  = z2 + 1048576;        // (8,128,32,32)  1048576
    float* cbn = z3 + 1048576;        // (512)
    float* h1  = cbn + 512;           // (8,128,32,32)  1048576
    float* h2  = h1 + 1048576;        // (8,64,64,64)   2097152

    float* out   = (float*)d_out;
    float* x_hat = out;               // 20447232
    float* e     = out + 20447232;    // 1048576
    float* idxf  = e + 1048576;       // 8192

    conv1_k<<<512, 256, 0, stream>>>(x, enc_w1, enc_b1, bn1_g, bn1_b, bn1_m, bn1_v, z1);
    conv2_k<<<256, 256, 0, stream>>>(z1, enc_w2, enc_b2, bn2_g, bn2_b, bn2_m, bn2_v, z2);
    conv3s1_k<0><<<256, 256, 0, stream>>>(z2, enc_w3, enc_b3, z3);
    cb_norms_k<<<2, 256, 0, stream>>>(cb, cbn);
    vq_k<<<256, 256, 0, stream>>>(z3, cb, cbn, e, idxf);
    conv3s1_k<2><<<256, 256, 0, stream>>>(e, dec_w1, dec_b1, h1);
    decT2_k<<<512, 256, 0, stream>>>(h1, dec_w2, dec_b2, h2);
    decT3_k<<<3072, 256, 0, stream>>>(h2, dec_w3, dec_b3, x_hat);
}

// Round 3
// 1077.985 us; speedup vs baseline: 6.2378x; 1.3238x over previous
//
#include <hip/hip_runtime.h>
#include <math.h>

#define BN_EPS 1e-5f

typedef __attribute__((ext_vector_type(8))) short bf16x8;
typedef __attribute__((ext_vector_type(4))) float f32x4;

__device__ __forceinline__ float sigmoidf_(float v) { return 1.0f / (1.0f + expf(-v)); }

__device__ __forceinline__ unsigned short f2bf(float f) {
    union { float f; unsigned u; } v; v.f = f;
    unsigned r = v.u + 0x7fffu + ((v.u >> 16) & 1u);   // RNE
    return (unsigned short)(r >> 16);
}
__device__ __forceinline__ float bf2f(unsigned short h) {
    union { unsigned u; float f; } v; v.u = ((unsigned)h) << 16;
    return v.f;
}

// ---------------------------------------------------------------------------
// conv1: 156->64, 4x4 s2 p1, BN+ReLU. in (8,156,128,128) -> out (8,64,64,64)
// ---------------------------------------------------------------------------
__global__ __launch_bounds__(256) void conv1_k(
    const float* __restrict__ x, const float* __restrict__ wg,
    const float* __restrict__ bias,
    const float* __restrict__ bng, const float* __restrict__ bnb,
    const float* __restrict__ bnm, const float* __restrict__ bnv,
    float* __restrict__ y)
{
    __shared__ float sW[64 * 68];
    __shared__ float sX[4][4][2][66];
    const int blk = blockIdx.x;
    const int b = blk >> 6, oh = blk & 63;
    const int t = threadIdx.x;
    const int ocg = t & 15, owg = t >> 4;
    const int oc0 = ocg * 4, ow0 = owg * 4;
    const int ih0 = oh * 2 - 1;

    float acc[4][4] = {};
    const int kq = t & 63, wq = t >> 6;

    for (int ic0 = 0; ic0 < 156; ic0 += 4) {
#pragma unroll
        for (int r = 0; r < 4; ++r) {
            int q4 = wq + r * 4;
            int gb = (q4 * 4) * 2496 + ic0 * 16 + kq;
            float4 v;
            v.x = wg[gb]; v.y = wg[gb + 2496]; v.z = wg[gb + 4992]; v.w = wg[gb + 7488];
            *(float4*)&sW[kq * 68 + q4 * 4] = v;
        }
        for (int li = t; li < 2080; li += 256) {
            int q = li % 130;
            int tmp = li / 130;
            int r = tmp & 3, icl = tmp >> 2;
            int iw = q - 1, ih = ih0 + r;
            float v = 0.0f;
            if ((unsigned)ih < 128u && (unsigned)iw < 128u)
                v = x[((size_t)(b * 156 + ic0 + icl) * 128 + ih) * 128 + iw];
            sX[icl][r][(iw & 1) ? 0 : 1][(iw + 1) >> 1] = v;
        }
        __syncthreads();
#pragma unroll
        for (int icl = 0; icl < 4; ++icl) {
#pragma unroll
            for (int kh = 0; kh < 4; ++kh) {
                float x0[5], x1[5];
#pragma unroll
                for (int q = 0; q < 5; ++q) {
                    x0[q] = sX[icl][kh][0][ow0 + q];
                    x1[q] = sX[icl][kh][1][ow0 + q];
                }
                const int kb = (icl * 16 + kh * 4) * 68 + oc0;
                float w0[4], w1[4], w2[4], w3[4];
                *(float4*)w0 = *(const float4*)&sW[kb];
                *(float4*)w1 = *(const float4*)&sW[kb + 68];
                *(float4*)w2 = *(const float4*)&sW[kb + 136];
                *(float4*)w3 = *(const float4*)&sW[kb + 204];
#pragma unroll
                for (int i = 0; i < 4; ++i)
#pragma unroll
                    for (int m = 0; m < 4; ++m) {
                        acc[i][m] = fmaf(w0[i], x0[m],     acc[i][m]);
                        acc[i][m] = fmaf(w1[i], x1[m],     acc[i][m]);
                        acc[i][m] = fmaf(w2[i], x0[m + 1], acc[i][m]);
                        acc[i][m] = fmaf(w3[i], x1[m + 1], acc[i][m]);
                    }
            }
        }
        __syncthreads();
    }
#pragma unroll
    for (int i = 0; i < 4; ++i) {
        int oc = oc0 + i;
        float s = bng[oc] / sqrtf(bnv[oc] + BN_EPS);
        float o = fmaf(bias[oc], s, bnb[oc] - bnm[oc] * s);
        float4 vv;
        vv.x = fmaxf(fmaf(acc[i][0], s, o), 0.0f);
        vv.y = fmaxf(fmaf(acc[i][1], s, o), 0.0f);
        vv.z = fmaxf(fmaf(acc[i][2], s, o), 0.0f);
        vv.w = fmaxf(fmaf(acc[i][3], s, o), 0.0f);
        *(float4*)&y[((size_t)(b * 64 + oc) * 64 + oh) * 64 + ow0] = vv;
    }
}

// ---------------------------------------------------------------------------
// conv2: 64->128, 4x4 s2 p1, BN+ReLU. (8,64,64,64) -> (8,128,32,32)
// ---------------------------------------------------------------------------
__global__ __launch_bounds__(256) void conv2_k(
    const float* __restrict__ x, const float* __restrict__ wg,
    const float* __restrict__ bias,
    const float* __restrict__ bng, const float* __restrict__ bnb,
    const float* __restrict__ bnm, const float* __restrict__ bnv,
    float* __restrict__ y)
{
    __shared__ float sW[64 * 132];
    __shared__ float sX[4][4][2][34];
    const int blk = blockIdx.x;
    const int b = blk >> 5, oh = blk & 31;
    const int t = threadIdx.x;
    const int ocg = t & 31, owg = t >> 5;
    const int oc0 = ocg * 4, ow0 = owg * 4;
    const int ih0 = oh * 2 - 1;

    float acc[4][4] = {};
    const int kq = t & 63, wq = t >> 6;

    for (int ic0 = 0; ic0 < 64; ic0 += 4) {
#pragma unroll
        for (int r = 0; r < 8; ++r) {
            int q4 = wq + r * 4;
            int gb = (q4 * 4) * 1024 + ic0 * 16 + kq;
            float4 v;
            v.x = wg[gb]; v.y = wg[gb + 1024]; v.z = wg[gb + 2048]; v.w = wg[gb + 3072];
            *(float4*)&sW[kq * 132 + q4 * 4] = v;
        }
        for (int li = t; li < 1056; li += 256) {
            int q = li % 66;
            int tmp = li / 66;
            int r = tmp & 3, icl = tmp >> 2;
            int iw = q - 1, ih = ih0 + r;
            float v = 0.0f;
            if ((unsigned)ih < 64u && (unsigned)iw < 64u)
                v = x[((size_t)(b * 64 + ic0 + icl) * 64 + ih) * 64 + iw];
            sX[icl][r][(iw & 1) ? 0 : 1][(iw + 1) >> 1] = v;
        }
        __syncthreads();
#pragma unroll
        for (int icl = 0; icl < 4; ++icl) {
#pragma unroll
            for (int kh = 0; kh < 4; ++kh) {
                float x0[5], x1[5];
#pragma unroll
                for (int q = 0; q < 5; ++q) {
                    x0[q] = sX[icl][kh][0][ow0 + q];
                    x1[q] = sX[icl][kh][1][ow0 + q];
                }
                const int kb = (icl * 16 + kh * 4) * 132 + oc0;
                float w0[4], w1[4], w2[4], w3[4];
                *(float4*)w0 = *(const float4*)&sW[kb];
                *(float4*)w1 = *(const float4*)&sW[kb + 132];
                *(float4*)w2 = *(const float4*)&sW[kb + 264];
                *(float4*)w3 = *(const float4*)&sW[kb + 396];
#pragma unroll
                for (int i = 0; i < 4; ++i)
#pragma unroll
                    for (int m = 0; m < 4; ++m) {
                        acc[i][m] = fmaf(w0[i], x0[m],     acc[i][m]);
                        acc[i][m] = fmaf(w1[i], x1[m],     acc[i][m]);
                        acc[i][m] = fmaf(w2[i], x0[m + 1], acc[i][m]);
                        acc[i][m] = fmaf(w3[i], x1[m + 1], acc[i][m]);
                    }
            }
        }
        __syncthreads();
    }
#pragma unroll
    for (int i = 0; i < 4; ++i) {
        int oc = oc0 + i;
        float s = bng[oc] / sqrtf(bnv[oc] + BN_EPS);
        float o = fmaf(bias[oc], s, bnb[oc] - bnm[oc] * s);
        float4 vv;
        vv.x = fmaxf(fmaf(acc[i][0], s, o), 0.0f);
        vv.y = fmaxf(fmaf(acc[i][1], s, o), 0.0f);
        vv.z = fmaxf(fmaf(acc[i][2], s, o), 0.0f);
        vv.w = fmaxf(fmaf(acc[i][3], s, o), 0.0f);
        *(float4*)&y[((size_t)(b * 128 + oc) * 32 + oh) * 32 + ow0] = vv;
    }
}

// ---------------------------------------------------------------------------
// conv3s1: 128->128, 3x3 s1 p1 on 32x32. MODE 0=bias only, 2=ReLU.
// ---------------------------------------------------------------------------
template <int MODE>
__global__ __launch_bounds__(256) void conv3s1_k(
    const float* __restrict__ x, const float* __restrict__ wg,
    const float* __restrict__ bias, float* __restrict__ y)
{
    __shared__ float sW[36 * 132];
    __shared__ float sX[4][3][36];
    const int blk = blockIdx.x;
    const int b = blk >> 5, oh = blk & 31;
    const int t = threadIdx.x;
    const int ocg = t & 31, owg = t >> 5;
    const int oc0 = ocg * 4, ow0 = owg * 4;
    const int ih0 = oh - 1;

    float acc[4][4] = {};

    for (int ic0 = 0; ic0 < 128; ic0 += 4) {
        for (int task = t; task < 1152; task += 256) {
            int k = task % 36;
            int qq = task / 36;
            int gb = (qq * 4) * 1152 + ic0 * 9 + k;
            float4 v;
            v.x = wg[gb]; v.y = wg[gb + 1152]; v.z = wg[gb + 2304]; v.w = wg[gb + 3456];
            *(float4*)&sW[k * 132 + qq * 4] = v;
        }
        for (int li = t; li < 408; li += 256) {
            int q = li % 34;
            int tmp = li / 34;
            int r = tmp % 3, icl = tmp / 3;
            int iw = q - 1, ih = ih0 + r;
            float v = 0.0f;
            if ((unsigned)ih < 32u && (unsigned)iw < 32u)
                v = x[((size_t)(b * 128 + ic0 + icl) * 32 + ih) * 32 + iw];
            sX[icl][r][q] = v;
        }
        __syncthreads();
#pragma unroll
        for (int icl = 0; icl < 4; ++icl) {
#pragma unroll
            for (int kh = 0; kh < 3; ++kh) {
                float xv[6];
#pragma unroll
                for (int q = 0; q < 6; ++q) xv[q] = sX[icl][kh][ow0 + q];
                const int kb = (icl * 9 + kh * 3) * 132 + oc0;
                float w0[4], w1[4], w2[4];
                *(float4*)w0 = *(const float4*)&sW[kb];
                *(float4*)w1 = *(const float4*)&sW[kb + 132];
                *(float4*)w2 = *(const float4*)&sW[kb + 264];
#pragma unroll
                for (int i = 0; i < 4; ++i)
#pragma unroll
                    for (int m = 0; m < 4; ++m) {
                        acc[i][m] = fmaf(w0[i], xv[m],     acc[i][m]);
                        acc[i][m] = fmaf(w1[i], xv[m + 1], acc[i][m]);
                        acc[i][m] = fmaf(w2[i], xv[m + 2], acc[i][m]);
                    }
            }
        }
        __syncthreads();
    }
#pragma unroll
    for (int i = 0; i < 4; ++i) {
        int oc = oc0 + i;
        float bz = bias[oc];
        float4 vv;
        float r0 = acc[i][0] + bz, r1 = acc[i][1] + bz, r2 = acc[i][2] + bz, r3 = acc[i][3] + bz;
        if (MODE == 2) { r0 = fmaxf(r0, 0.f); r1 = fmaxf(r1, 0.f); r2 = fmaxf(r2, 0.f); r3 = fmaxf(r3, 0.f); }
        vv.x = r0; vv.y = r1; vv.z = r2; vv.w = r3;
        *(float4*)&y[((size_t)(b * 128 + oc) * 32 + oh) * 32 + ow0] = vv;
    }
}

// ---------------------------------------------------------------------------
// decT2: convT 128->64, 4x4 s2 p1, ReLU. (8,128,32,32) -> (8,64,64,64)
// ---------------------------------------------------------------------------
__global__ __launch_bounds__(256) void decT2_k(
    const float* __restrict__ x, const float* __restrict__ wg,
    const float* __restrict__ bias, float* __restrict__ y)
{
    __shared__ float sW[64 * 68];
    __shared__ float sX[4][2][36];
    const int blk = blockIdx.x;
    const int b = blk >> 6, oh = blk & 63;
    const int t = threadIdx.x;
    const int ocg = t & 15, owg = t >> 4;
    const int oc0 = ocg * 4, ow0 = owg * 4;
    const int kh0 = (oh + 1) & 1;
    const int ih_a = (oh + 1 - kh0) >> 1;
    const int ih_b = ih_a - 1;

    float acc[4][4] = {};

    for (int ic0 = 0; ic0 < 128; ic0 += 4) {
        for (int r = 0; r < 16; ++r) {
            int li = t + 256 * r;
            int tap = li & 15, oc = (li >> 4) & 63, icl = li >> 10;
            sW[(icl * 16 + tap) * 68 + oc] = wg[(size_t)(ic0 + icl) * 1024 + oc * 16 + tap];
        }
        for (int li = t; li < 272; li += 256) {
            int q = li % 34;
            int tmp = li / 34;
            int r = tmp & 1, icl = tmp >> 1;
            int iw = q - 1, ih = ih_b + r;
            float v = 0.0f;
            if ((unsigned)ih < 32u && (unsigned)iw < 32u)
                v = x[((size_t)(b * 128 + ic0 + icl) * 32 + ih) * 32 + iw];
            sX[icl][r][q] = v;
        }
        __syncthreads();
#pragma unroll
        for (int icl = 0; icl < 4; ++icl) {
            float x0v[4], x1v[4];
            const int ib = ow0 >> 1;
#pragma unroll
            for (int q = 0; q < 4; ++q) { x0v[q] = sX[icl][0][ib + q]; x1v[q] = sX[icl][1][ib + q]; }
            const int kbA = (icl * 16 + kh0 * 4) * 68 + oc0;
            const int kbB = kbA + 8 * 68;
            float wA0[4], wA1[4], wA2[4], wA3[4], wB0[4], wB1[4], wB2[4], wB3[4];
            *(float4*)wA0 = *(const float4*)&sW[kbA];
            *(float4*)wA1 = *(const float4*)&sW[kbA + 68];
            *(float4*)wA2 = *(const float4*)&sW[kbA + 136];
            *(float4*)wA3 = *(const float4*)&sW[kbA + 204];
            *(float4*)wB0 = *(const float4*)&sW[kbB];
            *(float4*)wB1 = *(const float4*)&sW[kbB + 68];
            *(float4*)wB2 = *(const float4*)&sW[kbB + 136];
            *(float4*)wB3 = *(const float4*)&sW[kbB + 204];
#pragma unroll
            for (int i = 0; i < 4; ++i) {
                acc[i][0] = fmaf(wA1[i], x1v[1], acc[i][0]);
                acc[i][0] = fmaf(wA3[i], x1v[0], acc[i][0]);
                acc[i][0] = fmaf(wB1[i], x0v[1], acc[i][0]);
                acc[i][0] = fmaf(wB3[i], x0v[0], acc[i][0]);
                acc[i][1] = fmaf(wA0[i], x1v[2], acc[i][1]);
                acc[i][1] = fmaf(wA2[i], x1v[1], acc[i][1]);
                acc[i][1] = fmaf(wB0[i], x0v[2], acc[i][1]);
                acc[i][1] = fmaf(wB2[i], x0v[1], acc[i][1]);
                acc[i][2] = fmaf(wA1[i], x1v[2], acc[i][2]);
                acc[i][2] = fmaf(wA3[i], x1v[1], acc[i][2]);
                acc[i][2] = fmaf(wB1[i], x0v[2], acc[i][2]);
                acc[i][2] = fmaf(wB3[i], x0v[1], acc[i][2]);
                acc[i][3] = fmaf(wA0[i], x1v[3], acc[i][3]);
                acc[i][3] = fmaf(wA2[i], x1v[2], acc[i][3]);
                acc[i][3] = fmaf(wB0[i], x0v[3], acc[i][3]);
                acc[i][3] = fmaf(wB2[i], x0v[2], acc[i][3]);
            }
        }
        __syncthreads();
    }
#pragma unroll
    for (int i = 0; i < 4; ++i) {
        int oc = oc0 + i;
        float bz = bias[oc];
        float4 vv;
        vv.x = fmaxf(acc[i][0] + bz, 0.f);
        vv.y = fmaxf(acc[i][1] + bz, 0.f);
        vv.z = fmaxf(acc[i][2] + bz, 0.f);
        vv.w = fmaxf(acc[i][3] + bz, 0.f);
        *(float4*)&y[((size_t)(b * 64 + oc) * 64 + oh) * 64 + ow0] = vv;
    }
}

// ---------------------------------------------------------------------------
// h2_cvt: h2 fp32 NCHW (8,64,64,64) -> padded NHWC bf16 hi/lo [8][66][66][64]
// Block per (b, padded row hp). Borders written as zero every launch.
// ---------------------------------------------------------------------------
__global__ __launch_bounds__(256) void h2_cvt(
    const float* __restrict__ h2,
    unsigned short* __restrict__ ph, unsigned short* __restrict__ pl)
{
    __shared__ float sX[64 * 65];   // [ic][w], stride 65 kills bank conflicts
    const int bid = blockIdx.x;
    const int b = bid / 66, hp = bid % 66;
    const bool interior = (hp >= 1 && hp <= 64);
    if (interior) {
        for (int i = threadIdx.x; i < 4096; i += 256) {
            int ic = i >> 6, w = i & 63;
            sX[ic * 65 + w] = h2[((size_t)(b * 64 + ic) * 64 + (hp - 1)) * 64 + w];
        }
    }
    __syncthreads();
    const size_t base = ((size_t)(b * 66) + hp) * 66 * 64;
    for (int i = threadIdx.x; i < 4224; i += 256) {   // 66 wp x 64 ic
        int wp = i >> 6, ic = i & 63;
        float v = 0.0f;
        if (interior && wp >= 1 && wp <= 64) v = sX[ic * 65 + (wp - 1)];
        unsigned short h = f2bf(v);
        ph[base + i] = h;
        pl[base + i] = f2bf(v - bf2f(h));
    }
}

// ---------------------------------------------------------------------------
// prep_w3: pack dec_w3 (64 in, 156 out, 4, 4) into MFMA B-fragment order,
// split bf16 hi/lo. Per parity class c=rh*2+rw: B_c[k=tau*64+ic][n=oc],
// tap tau=(dh,dw): kh=3-rh-2dh, kw=3-rw-2dw. Layout:
// record id = ((c*8+kk)*10+nf)*64 + lane; each record 8 bf16 (k-contig).
// ---------------------------------------------------------------------------
__global__ __launch_bounds__(256) void prep_w3(
    const float* __restrict__ w3,
    unsigned short* __restrict__ Bh, unsigned short* __restrict__ Bl)
{
    int id = blockIdx.x * 256 + threadIdx.x;
    if (id >= 20480) return;       // 4 cls * 8 kk * 10 nf * 64 lanes
    int l = id & 63;
    int nf = (id >> 6) % 10;
    int kk = (id / 640) & 7;
    int c = id / 5120;
    int rh = c >> 1, rw = c & 1;
    int n = nf * 16 + (l & 15);
    int k0 = kk * 32 + (l >> 4) * 8;
    size_t off = (size_t)id * 8;
#pragma unroll
    for (int j = 0; j < 8; ++j) {
        int k = k0 + j;
        int ic = k & 63, tau = k >> 6;
        int dh = tau >> 1, dw = tau & 1;
        int kh = 3 - rh - 2 * dh, kw = 3 - rw - 2 * dw;
        float v = (n < 156) ? w3[((size_t)(ic * 156 + n) * 4 + kh) * 4 + kw] : 0.0f;
        unsigned short h = f2bf(v);
        Bh[off + j] = h;
        Bl[off + j] = f2bf(v - bf2f(h));
    }
}

// ---------------------------------------------------------------------------
// decT3_mfma: convT 64->156 s2 p1 + sigmoid via split-bf16 implicit GEMM.
// Block = (b, q, rh): output row oh=2q+rh, BOTH ow-parity classes.
// Per class: M=64 p-positions, N=160 (156 padded), K=256 (4 taps x 64 ic).
// 4 waves = 2 M-halves x 2 N-halves; wave tile: M32(2 frags) x N80(5 frags).
// C = Ah*Bh + Ah*Bl + Al*Bh, fp32 accum. Epilogue: bias+sigmoid -> LDS
// transpose (2 passes of 80 oc) -> contiguous 128-float NCHW row stores.
// ---------------------------------------------------------------------------
__global__ __launch_bounds__(256) void decT3_mfma(
    const unsigned short* __restrict__ ah, const unsigned short* __restrict__ al,
    const unsigned short* __restrict__ Bh, const unsigned short* __restrict__ Bl,
    const float* __restrict__ bias, float* __restrict__ y)
{
    const int bid = blockIdx.x;
    const int b = bid >> 7;
    const int q = (bid >> 1) & 63;
    const int rh = bid & 1;
    const int oh = 2 * q + rh;
    const int t = threadIdx.x;
    const int l = t & 63;
    const int wv = t >> 6;
    const int mh = wv & 1, nh = wv >> 1;
    const int mo = mh * 32;
    const int lr = l & 15;     // A-row / B-col within fragment
    const int lk = l >> 4;     // k-quad
    const int icb0 = lk * 8;

    f32x4 acc[2][2][5] = {};   // [cls(rw)][mf][nfl]

    for (int tau = 0; tau < 4; ++tau) {
        const int dh = tau >> 1, dw = tau & 1;
        const size_t rowbase = ((size_t)(b * 66) + (q + rh + dh)) * 66;
#pragma unroll
        for (int ks = 0; ks < 2; ++ks) {
            const int icb = ks * 32 + icb0;
            bf16x8 Ah[2][2], Al[2][2];
#pragma unroll
            for (int cls = 0; cls < 2; ++cls)
#pragma unroll
                for (int mf = 0; mf < 2; ++mf) {
                    const int p = mo + mf * 16 + lr;
                    const size_t off = (rowbase + (p + cls + dw)) * 64 + icb;
                    Ah[cls][mf] = *(const bf16x8*)(ah + off);
                    Al[cls][mf] = *(const bf16x8*)(al + off);
                }
            const int kk = tau * 2 + ks;
#pragma unroll
            for (int nfl = 0; nfl < 5; ++nfl) {
                const int nf = nh * 5 + nfl;
#pragma unroll
                for (int cls = 0; cls < 2; ++cls) {
                    const int c = rh * 2 + cls;
                    const size_t boff = (((size_t)(c * 8 + kk)) * 10 + nf) * 512 + l * 8;
                    bf16x8 bh = *(const bf16x8*)(Bh + boff);
                    bf16x8 bl = *(const bf16x8*)(Bl + boff);
#pragma unroll
                    for (int mf = 0; mf < 2; ++mf) {
                        acc[cls][mf][nfl] = __builtin_amdgcn_mfma_f32_16x16x32_bf16(Ah[cls][mf], bh, acc[cls][mf][nfl], 0, 0, 0);
                        acc[cls][mf][nfl] = __builtin_amdgcn_mfma_f32_16x16x32_bf16(Ah[cls][mf], bl, acc[cls][mf][nfl], 0, 0, 0);
                        acc[cls][mf][nfl] = __builtin_amdgcn_mfma_f32_16x16x32_bf16(Al[cls][mf], bh, acc[cls][mf][nfl], 0, 0, 0);
                    }
                }
            }
        }
    }

    __shared__ float sC[128 * 81];   // [ow][ocl], stride 81 (odd) -> clean banks
#pragma unroll
    for (int pass = 0; pass < 2; ++pass) {
        __syncthreads();
        if (nh == pass) {
#pragma unroll
            for (int cls = 0; cls < 2; ++cls)
#pragma unroll
            for (int mf = 0; mf < 2; ++mf)
#pragma unroll
            for (int nfl = 0; nfl < 5; ++nfl) {
                const int ocl = nfl * 16 + lr;
                const int oc = nh * 80 + ocl;
                const float bz = (oc < 156) ? bias[oc] : 0.0f;
#pragma unroll
                for (int r = 0; r < 4; ++r) {
                    const int p = mo + mf * 16 + lk * 4 + r;
                    const int ow = 2 * p + cls;
                    sC[ow * 81 + ocl] = sigmoidf_(acc[cls][mf][nfl][r] + bz);
                }
            }
        }
        __syncthreads();
        const int ocbase = pass * 80;
        for (int i = t; i < 80 * 128; i += 256) {
            const int ow = i & 127, ocl = i >> 7;
            const int oc = ocbase + ocl;
            if (oc < 156)
                y[(((size_t)(b * 156 + oc)) * 128 + oh) * 128 + ow] = sC[ow * 81 + ocl];
        }
    }
}

// ---------------------------------------------------------------------------
// VQ (unchanged, bit-identical numerics)
// ---------------------------------------------------------------------------
__global__ __launch_bounds__(256) void cb_norms_k(const float* __restrict__ cb,
                                                  float* __restrict__ cbn)
{
    int k = blockIdx.x * 256 + threadIdx.x;
    if (k >= 512) return;
    const float* cp = cb + (size_t)k * 128;
    float s = 0.0f;
#pragma unroll
    for (int d = 0; d < 128; ++d) s = fmaf(cp[d], cp[d], s);
    cbn[k] = s;
}

__global__ __launch_bounds__(256) void vq_k(
    const float* __restrict__ z, const float* __restrict__ cb,
    const float* __restrict__ cbn,
    float* __restrict__ e, float* __restrict__ idxf)
{
    const int blk = blockIdx.x;
    const int b = blk >> 5;
    const int n0 = (blk & 31) << 5;
    const int t = threadIdx.x;
    const int nl = t & 31, kq = t >> 5;
    const int n = n0 + nl;

    float zr[128];
#pragma unroll
    for (int d = 0; d < 128; ++d) zr[d] = z[(size_t)(b * 128 + d) * 1024 + n];
    float zn = 0.0f;
#pragma unroll
    for (int d = 0; d < 128; ++d) zn = fmaf(zr[d], zr[d], zn);

    float best = 3.4e38f;
    int bk = kq * 64;
    for (int k = kq * 64; k < kq * 64 + 64; ++k) {
        const float4* cp = (const float4*)(cb + (size_t)k * 128);
        float dot = 0.0f;
#pragma unroll
        for (int j = 0; j < 32; ++j) {
            float4 c = cp[j];
            dot = fmaf(zr[4 * j + 0], c.x, dot);
            dot = fmaf(zr[4 * j + 1], c.y, dot);
            dot = fmaf(zr[4 * j + 2], c.z, dot);
            dot = fmaf(zr[4 * j + 3], c.w, dot);
        }
        float dist = (zn - 2.0f * dot) + cbn[k];
        if (dist < best) { best = dist; bk = k; }
    }
    __shared__ float sd[8][32];
    __shared__ int si[8][32];
    sd[kq][nl] = best;
    si[kq][nl] = bk;
    __syncthreads();
    if (t < 32) {
#pragma unroll
        for (int q = 1; q < 8; ++q) {
            float d2 = sd[q][nl];
            if (d2 < best) { best = d2; bk = si[q][nl]; }
        }
        si[0][nl] = bk;
        idxf[b * 1024 + n] = (float)bk;
    }
    __syncthreads();
    for (int li = t; li < 4096; li += 256) {
        int d = li >> 5, nn = li & 31;
        e[(size_t)(b * 128 + d) * 1024 + n0 + nn] = cb[(size_t)si[0][nn] * 128 + d];
    }
}

// ---------------------------------------------------------------------------
extern "C" void kernel_launch(void* const* d_in, const int* in_sizes, int n_in,
                              void* d_out, int out_size, void* d_ws, size_t ws_size,
                              hipStream_t stream)
{
    const float* x      = (const float*)d_in[0];
    const float* enc_w1 = (const float*)d_in[1];
    const float* enc_b1 = (const float*)d_in[2];
    const float* bn1_g  = (const float*)d_in[3];
    const float* bn1_b  = (const float*)d_in[4];
    const float* bn1_m  = (const float*)d_in[5];
    const float* bn1_v  = (const float*)d_in[6];
    const float* enc_w2 = (const float*)d_in[7];
    const float* enc_b2 = (const float*)d_in[8];
    const float* bn2_g  = (const float*)d_in[9];
    const float* bn2_b  = (const float*)d_in[10];
    const float* bn2_m  = (const float*)d_in[11];
    const float* bn2_v  = (const float*)d_in[12];
    const float* enc_w3 = (const float*)d_in[13];
    const float* enc_b3 = (const float*)d_in[14];
    const float* cb     = (const float*)d_in[15];
    const float* dec_w1 = (const float*)d_in[16];
    const float* dec_b1 = (const float*)d_in[17];
    const float* dec_w2 = (const float*)d_in[18];
    const float* dec_b2 = (const float*)d_in[19];
    const float* dec_w3 = (const float*)d_in[20];
    const float* dec_b3 = (const float*)d_in[21];

    float* ws = (float*)d_ws;
    float* z1  = ws;                  // (8,64,64,64)   2097152  (dead after conv2)
    float* z2  = z1 + 2097152;        // (8,128,32,32)  1048576  (dead after conv3)
    float* z3  = z2 + 1048576;        // (8,128,32,32)  1048576
    float* cbn = z3 + 1048576;        // (512)
    float* h1  = cbn + 512;           // (8,128,32,32)  1048576
    float* h2  = h1 + 1048576;        // (8,64,64,64)   2097152
    // h2 padded NHWC bf16 hi/lo overlays z1/z2 (dead by then):
    //   2,230,272 ushorts each = 2,230,272 floats total < 3,145,728
    unsigned short* h2p_hi = (unsigned short*)ws;
    unsigned short* h2p_lo = (unsigned short*)(ws + 1115136);
    // packed dec_w3 fragments after h2: 163,840 ushorts each
    unsigned short* B3h = (unsigned short*)(ws + 7340544);
    unsigned short* B3l = (unsigned short*)(ws + 7340544 + 81920);

    float* out   = (float*)d_out;
    float* x_hat = out;               // 20447232
    float* e     = out + 20447232;    // 1048576
    float* idxf  = e + 1048576;       // 8192

    prep_w3<<<80, 256, 0, stream>>>(dec_w3, B3h, B3l);
    conv1_k<<<512, 256, 0, stream>>>(x, enc_w1, enc_b1, bn1_g, bn1_b, bn1_m, bn1_v, z1);
    conv2_k<<<256, 256, 0, stream>>>(z1, enc_w2, enc_b2, bn2_g, bn2_b, bn2_m, bn2_v, z2);
    conv3s1_k<0><<<256, 256, 0, stream>>>(z2, enc_w3, enc_b3, z3);
    cb_norms_k<<<2, 256, 0, stream>>>(cb, cbn);
    vq_k<<<256, 256, 0, stream>>>(z3, cb, cbn, e, idxf);
    conv3s1_k<2><<<256, 256, 0, stream>>>(e, dec_w1, dec_b1, h1);
    decT2_k<<<512, 256, 0, stream>>>(h1, dec_w2, dec_b2, h2);
    h2_cvt<<<528, 256, 0, stream>>>(h2, h2p_hi, h2p_lo);
    decT3_mfma<<<1024, 256, 0, stream>>>(h2p_hi, h2p_lo, B3h, B3l, dec_b3, x_hat);
}

// Round 5
// 1029.447 us; speedup vs baseline: 6.5319x; 1.0471x over previous
//
#include <hip/hip_runtime.h>
#include <math.h>

#define BN_EPS 1e-5f

typedef __attribute__((ext_vector_type(8))) short bf16x8;
typedef __attribute__((ext_vector_type(4))) float f32x4;

__device__ __forceinline__ float sigmoidf_(float v) { return 1.0f / (1.0f + expf(-v)); }

__device__ __forceinline__ unsigned short f2bf(float f) {
    union { float f; unsigned u; } v; v.f = f;
    unsigned r = v.u + 0x7fffu + ((v.u >> 16) & 1u);   // RNE
    return (unsigned short)(r >> 16);
}
__device__ __forceinline__ float bf2f(unsigned short h) {
    union { unsigned u; float f; } v; v.u = ((unsigned)h) << 16;
    return v.f;
}

// ---------------------------------------------------------------------------
// prep_w1: pack enc_w1 (64 oc, 156 ic, 4, 4) into MFMA B-fragment order,
// 3 bf16 limbs. K-order: kk = chunk*8 + j (chunk = 16-ic group, 10 of them);
// kstep j covers taps {2j, 2j+1}; klocal = (l>>4)*8+jj: tap = 2j+(klocal>>4),
// ic = chunk*16 + (klocal&15). Record: ((kk*4+nf)*64+l)*8 + jj.
// ---------------------------------------------------------------------------
__global__ __launch_bounds__(256) void prep_w1(
    const float* __restrict__ w1, unsigned short* __restrict__ Bw)
{
    int id = blockIdx.x * 256 + threadIdx.x;
    if (id >= 20480) return;                 // 80 kk * 4 nf * 64 lanes
    int l = id & 63;
    int nf = (id >> 6) & 3;
    int kk = id >> 8;
    int oc = nf * 16 + (l & 15);
    int chunk = kk >> 3, j = kk & 7;
    size_t off = (size_t)id * 8;
#pragma unroll
    for (int jj = 0; jj < 8; ++jj) {
        int klocal = ((l >> 4) << 3) + jj;   // 0..31
        int tap = 2 * j + (klocal >> 4);
        int ic = chunk * 16 + (klocal & 15);
        int kh = tap >> 2, kw = tap & 3;
        float v = (ic < 156) ? w1[((size_t)(oc * 156 + ic) * 4 + kh) * 4 + kw] : 0.0f;
        unsigned short b0 = f2bf(v);
        float r1 = v - bf2f(b0);
        unsigned short b1 = f2bf(r1);
        unsigned short b2 = f2bf(r1 - bf2f(b1));
        Bw[off + jj]          = b0;
        Bw[163840 + off + jj] = b1;
        Bw[327680 + off + jj] = b2;
    }
}

// ---------------------------------------------------------------------------
// conv1_mfma: 156->64, 4x4 s2 p1, BN+ReLU via 6-term 3-limb bf16 MFMA GEMM.
// Block = (b, oh): M=64 ow, N=64 oc, K=160ic*16taps. 4 waves = 2mh x 2nh,
// wave tile M32 x N32. LDS: sA[3 limbs][4 rows][2 parity][66][16 ic] bf16.
// Tap (kh,kw) at output p reads row kh, parity kw&1, idx p+(kw>>1).
// C = a0b0+a0b1+a1b0+a1b1+a0b2+a2b0 (err ~2^-23). Epilogue: LDS transpose.
// ---------------------------------------------------------------------------
__global__ __launch_bounds__(256) void conv1_mfma(
    const float* __restrict__ x, const unsigned short* __restrict__ Bw,
    const float* __restrict__ bias,
    const float* __restrict__ bng, const float* __restrict__ bnb,
    const float* __restrict__ bnm, const float* __restrict__ bnv,
    float* __restrict__ y)
{
    __shared__ unsigned short sA[3][4][2][66][16];
    __shared__ float sC[64][65];
    const int blk = blockIdx.x;
    const int b = blk >> 6, oh = blk & 63;
    const int t = threadIdx.x;
    const int l = t & 63, wv = t >> 6;
    const int mh = wv & 1, nh = wv >> 1;
    const int mo = mh * 32;
    const int lr = l & 15, lk = l >> 4;
    const int ih0 = 2 * oh - 1;
    const int tap_sel = lk >> 1;          // 0 or 1: which tap of the pair
    const int ic8 = (lk & 1) * 8;

    f32x4 acc[2][2] = {};                 // [mf][nfl]

    for (int c = 0; c < 10; ++c) {
        __syncthreads();
        // stage 16 ic: slot = ((il*4 + r)*2 + par)*66 + idx, 8448 = 33*256
#pragma unroll 1
        for (int s = 0; s < 33; ++s) {
            int slot = t + s * 256;
            int idx = slot % 66;
            int rem = slot / 66;
            int par = rem & 1, r = (rem >> 1) & 3, il = rem >> 3;
            int ic = c * 16 + il;
            int iw = (par == 0) ? 2 * idx - 1 : 2 * idx;
            int ih = ih0 + r;
            float v = 0.0f;
            if (ic < 156 && (unsigned)ih < 128u && (unsigned)iw < 128u)
                v = x[((size_t)(b * 156 + ic) * 128 + ih) * 128 + iw];
            unsigned short a0 = f2bf(v);
            float r1 = v - bf2f(a0);
            unsigned short a1 = f2bf(r1);
            unsigned short a2 = f2bf(r1 - bf2f(a1));
            sA[0][r][par][idx][il] = a0;
            sA[1][r][par][idx][il] = a1;
            sA[2][r][par][idx][il] = a2;
        }
        __syncthreads();
#pragma unroll
        for (int j = 0; j < 8; ++j) {
            const int tap = 2 * j + tap_sel;
            const int r = tap >> 2, kw = tap & 3;
            const int base = ((r * 2 + (kw & 1)) * 66 + (kw >> 1)) * 16 + ic8;
            bf16x8 A0[2], A1[2], A2[2];
#pragma unroll
            for (int mf = 0; mf < 2; ++mf) {
                const int off = base + (mo + mf * 16 + lr) * 16;
                A0[mf] = *(const bf16x8*)&sA[0][0][0][0][off];
                A1[mf] = *(const bf16x8*)&sA[1][0][0][0][off];
                A2[mf] = *(const bf16x8*)&sA[2][0][0][0][off];
            }
            const int kk = c * 8 + j;
#pragma unroll
            for (int nfl = 0; nfl < 2; ++nfl) {
                const int nf = nh * 2 + nfl;
                const size_t boff = ((size_t)(kk * 4 + nf) * 64 + l) * 8;
                bf16x8 B0 = *(const bf16x8*)(Bw + boff);
                bf16x8 B1 = *(const bf16x8*)(Bw + 163840 + boff);
                bf16x8 B2 = *(const bf16x8*)(Bw + 327680 + boff);
#pragma unroll
                for (int mf = 0; mf < 2; ++mf) {
                    acc[mf][nfl] = __builtin_amdgcn_mfma_f32_16x16x32_bf16(A0[mf], B0, acc[mf][nfl], 0, 0, 0);
                    acc[mf][nfl] = __builtin_amdgcn_mfma_f32_16x16x32_bf16(A0[mf], B1, acc[mf][nfl], 0, 0, 0);
                    acc[mf][nfl] = __builtin_amdgcn_mfma_f32_16x16x32_bf16(A1[mf], B0, acc[mf][nfl], 0, 0, 0);
                    acc[mf][nfl] = __builtin_amdgcn_mfma_f32_16x16x32_bf16(A1[mf], B1, acc[mf][nfl], 0, 0, 0);
                    acc[mf][nfl] = __builtin_amdgcn_mfma_f32_16x16x32_bf16(A0[mf], B2, acc[mf][nfl], 0, 0, 0);
                    acc[mf][nfl] = __builtin_amdgcn_mfma_f32_16x16x32_bf16(A2[mf], B0, acc[mf][nfl], 0, 0, 0);
                }
            }
        }
    }

    __syncthreads();
#pragma unroll
    for (int mf = 0; mf < 2; ++mf)
#pragma unroll
        for (int nfl = 0; nfl < 2; ++nfl) {
            const int oc = nh * 32 + nfl * 16 + lr;
#pragma unroll
            for (int r = 0; r < 4; ++r) {
                const int p = mo + mf * 16 + lk * 4 + r;
                sC[p][oc] = acc[mf][nfl][r];
            }
        }
    __syncthreads();
    for (int i = t; i < 4096; i += 256) {
        const int oc = i >> 6, ow = i & 63;
        float s = bng[oc] / sqrtf(bnv[oc] + BN_EPS);
        float o = bnb[oc] - bnm[oc] * s;
        float r = fmaxf((sC[ow][oc] + bias[oc]) * s + o, 0.0f);
        y[((size_t)(b * 64 + oc) * 64 + oh) * 64 + ow] = r;
    }
}

// ---------------------------------------------------------------------------
// conv2: 64->128, 4x4 s2 p1, BN+ReLU. (8,64,64,64) -> (8,128,32,32)
// ---------------------------------------------------------------------------
__global__ __launch_bounds__(256) void conv2_k(
    const float* __restrict__ x, const float* __restrict__ wg,
    const float* __restrict__ bias,
    const float* __restrict__ bng, const float* __restrict__ bnb,
    const float* __restrict__ bnm, const float* __restrict__ bnv,
    float* __restrict__ y)
{
    __shared__ float sW[64 * 132];
    __shared__ float sX[4][4][2][34];
    const int blk = blockIdx.x;
    const int b = blk >> 5, oh = blk & 31;
    const int t = threadIdx.x;
    const int ocg = t & 31, owg = t >> 5;
    const int oc0 = ocg * 4, ow0 = owg * 4;
    const int ih0 = oh * 2 - 1;

    float acc[4][4] = {};
    const int kq = t & 63, wq = t >> 6;

    for (int ic0 = 0; ic0 < 64; ic0 += 4) {
#pragma unroll
        for (int r = 0; r < 8; ++r) {
            int q4 = wq + r * 4;
            int gb = (q4 * 4) * 1024 + ic0 * 16 + kq;
            float4 v;
            v.x = wg[gb]; v.y = wg[gb + 1024]; v.z = wg[gb + 2048]; v.w = wg[gb + 3072];
            *(float4*)&sW[kq * 132 + q4 * 4] = v;
        }
        for (int li = t; li < 1056; li += 256) {
            int q = li % 66;
            int tmp = li / 66;
            int r = tmp & 3, icl = tmp >> 2;
            int iw = q - 1, ih = ih0 + r;
            float v = 0.0f;
            if ((unsigned)ih < 64u && (unsigned)iw < 64u)
                v = x[((size_t)(b * 64 + ic0 + icl) * 64 + ih) * 64 + iw];
            sX[icl][r][(iw & 1) ? 0 : 1][(iw + 1) >> 1] = v;
        }
        __syncthreads();
#pragma unroll
        for (int icl = 0; icl < 4; ++icl) {
#pragma unroll
            for (int kh = 0; kh < 4; ++kh) {
                float x0[5], x1[5];
#pragma unroll
                for (int q = 0; q < 5; ++q) {
                    x0[q] = sX[icl][kh][0][ow0 + q];
                    x1[q] = sX[icl][kh][1][ow0 + q];
                }
                const int kb = (icl * 16 + kh * 4) * 132 + oc0;
                float w0[4], w1[4], w2[4], w3[4];
                *(float4*)w0 = *(const float4*)&sW[kb];
                *(float4*)w1 = *(const float4*)&sW[kb + 132];
                *(float4*)w2 = *(const float4*)&sW[kb + 264];
                *(float4*)w3 = *(const float4*)&sW[kb + 396];
#pragma unroll
                for (int i = 0; i < 4; ++i)
#pragma unroll
                    for (int m = 0; m < 4; ++m) {
                        acc[i][m] = fmaf(w0[i], x0[m],     acc[i][m]);
                        acc[i][m] = fmaf(w1[i], x1[m],     acc[i][m]);
                        acc[i][m] = fmaf(w2[i], x0[m + 1], acc[i][m]);
                        acc[i][m] = fmaf(w3[i], x1[m + 1], acc[i][m]);
                    }
            }
        }
        __syncthreads();
    }
#pragma unroll
    for (int i = 0; i < 4; ++i) {
        int oc = oc0 + i;
        float s = bng[oc] / sqrtf(bnv[oc] + BN_EPS);
        float o = fmaf(bias[oc], s, bnb[oc] - bnm[oc] * s);
        float4 vv;
        vv.x = fmaxf(fmaf(acc[i][0], s, o), 0.0f);
        vv.y = fmaxf(fmaf(acc[i][1], s, o), 0.0f);
        vv.z = fmaxf(fmaf(acc[i][2], s, o), 0.0f);
        vv.w = fmaxf(fmaf(acc[i][3], s, o), 0.0f);
        *(float4*)&y[((size_t)(b * 128 + oc) * 32 + oh) * 32 + ow0] = vv;
    }
}

// ---------------------------------------------------------------------------
// conv3s1: 128->128, 3x3 s1 p1 on 32x32. MODE 0=bias only, 2=ReLU.
// ---------------------------------------------------------------------------
template <int MODE>
__global__ __launch_bounds__(256) void conv3s1_k(
    const float* __restrict__ x, const float* __restrict__ wg,
    const float* __restrict__ bias, float* __restrict__ y)
{
    __shared__ float sW[36 * 132];
    __shared__ float sX[4][3][36];
    const int blk = blockIdx.x;
    const int b = blk >> 5, oh = blk & 31;
    const int t = threadIdx.x;
    const int ocg = t & 31, owg = t >> 5;
    const int oc0 = ocg * 4, ow0 = owg * 4;
    const int ih0 = oh - 1;

    float acc[4][4] = {};

    for (int ic0 = 0; ic0 < 128; ic0 += 4) {
        for (int task = t; task < 1152; task += 256) {
            int k = task % 36;
            int qq = task / 36;
            int gb = (qq * 4) * 1152 + ic0 * 9 + k;
            float4 v;
            v.x = wg[gb]; v.y = wg[gb + 1152]; v.z = wg[gb + 2304]; v.w = wg[gb + 3456];
            *(float4*)&sW[k * 132 + qq * 4] = v;
        }
        for (int li = t; li < 408; li += 256) {
            int q = li % 34;
            int tmp = li / 34;
            int r = tmp % 3, icl = tmp / 3;
            int iw = q - 1, ih = ih0 + r;
            float v = 0.0f;
            if ((unsigned)ih < 32u && (unsigned)iw < 32u)
                v = x[((size_t)(b * 128 + ic0 + icl) * 32 + ih) * 32 + iw];
            sX[icl][r][q] = v;
        }
        __syncthreads();
#pragma unroll
        for (int icl = 0; icl < 4; ++icl) {
#pragma unroll
            for (int kh = 0; kh < 3; ++kh) {
                float xv[6];
#pragma unroll
                for (int q = 0; q < 6; ++q) xv[q] = sX[icl][kh][ow0 + q];
                const int kb = (icl * 9 + kh * 3) * 132 + oc0;
                float w0[4], w1[4], w2[4];
                *(float4*)w0 = *(const float4*)&sW[kb];
                *(float4*)w1 = *(const float4*)&sW[kb + 132];
                *(float4*)w2 = *(const float4*)&sW[kb + 264];
#pragma unroll
                for (int i = 0; i < 4; ++i)
#pragma unroll
                    for (int m = 0; m < 4; ++m) {
                        acc[i][m] = fmaf(w0[i], xv[m],     acc[i][m]);
                        acc[i][m] = fmaf(w1[i], xv[m + 1], acc[i][m]);
                        acc[i][m] = fmaf(w2[i], xv[m + 2], acc[i][m]);
                    }
            }
        }
        __syncthreads();
    }
#pragma unroll
    for (int i = 0; i < 4; ++i) {
        int oc = oc0 + i;
        float bz = bias[oc];
        float4 vv;
        float r0 = acc[i][0] + bz, r1 = acc[i][1] + bz, r2 = acc[i][2] + bz, r3 = acc[i][3] + bz;
        if (MODE == 2) { r0 = fmaxf(r0, 0.f); r1 = fmaxf(r1, 0.f); r2 = fmaxf(r2, 0.f); r3 = fmaxf(r3, 0.f); }
        vv.x = r0; vv.y = r1; vv.z = r2; vv.w = r3;
        *(float4*)&y[((size_t)(b * 128 + oc) * 32 + oh) * 32 + ow0] = vv;
    }
}

// ---------------------------------------------------------------------------
// decT2: convT 128->64, 4x4 s2 p1, ReLU. (8,128,32,32) -> (8,64,64,64)
// ---------------------------------------------------------------------------
__global__ __launch_bounds__(256) void decT2_k(
    const float* __restrict__ x, const float* __restrict__ wg,
    const float* __restrict__ bias, float* __restrict__ y)
{
    __shared__ float sW[64 * 68];
    __shared__ float sX[4][2][36];
    const int blk = blockIdx.x;
    const int b = blk >> 6, oh = blk & 63;
    const int t = threadIdx.x;
    const int ocg = t & 15, owg = t >> 4;
    const int oc0 = ocg * 4, ow0 = owg * 4;
    const int kh0 = (oh + 1) & 1;
    const int ih_a = (oh + 1 - kh0) >> 1;
    const int ih_b = ih_a - 1;

    float acc[4][4] = {};

    for (int ic0 = 0; ic0 < 128; ic0 += 4) {
        for (int r = 0; r < 16; ++r) {
            int li = t + 256 * r;
            int tap = li & 15, oc = (li >> 4) & 63, icl = li >> 10;
            sW[(icl * 16 + tap) * 68 + oc] = wg[(size_t)(ic0 + icl) * 1024 + oc * 16 + tap];
        }
        for (int li = t; li < 272; li += 256) {
            int q = li % 34;
            int tmp = li / 34;
            int r = tmp & 1, icl = tmp >> 1;
            int iw = q - 1, ih = ih_b + r;
            float v = 0.0f;
            if ((unsigned)ih < 32u && (unsigned)iw < 32u)
                v = x[((size_t)(b * 128 + ic0 + icl) * 32 + ih) * 32 + iw];
            sX[icl][r][q] = v;
        }
        __syncthreads();
#pragma unroll
        for (int icl = 0; icl < 4; ++icl) {
            float x0v[4], x1v[4];
            const int ib = ow0 >> 1;
#pragma unroll
            for (int q = 0; q < 4; ++q) { x0v[q] = sX[icl][0][ib + q]; x1v[q] = sX[icl][1][ib + q]; }
            const int kbA = (icl * 16 + kh0 * 4) * 68 + oc0;
            const int kbB = kbA + 8 * 68;
            float wA0[4], wA1[4], wA2[4], wA3[4], wB0[4], wB1[4], wB2[4], wB3[4];
            *(float4*)wA0 = *(const float4*)&sW[kbA];
            *(float4*)wA1 = *(const float4*)&sW[kbA + 68];
            *(float4*)wA2 = *(const float4*)&sW[kbA + 136];
            *(float4*)wA3 = *(const float4*)&sW[kbA + 204];
            *(float4*)wB0 = *(const float4*)&sW[kbB];
            *(float4*)wB1 = *(const float4*)&sW[kbB + 68];
            *(float4*)wB2 = *(const float4*)&sW[kbB + 136];
            *(float4*)wB3 = *(const float4*)&sW[kbB + 204];
#pragma unroll
            for (int i = 0; i < 4; ++i) {
                acc[i][0] = fmaf(wA1[i], x1v[1], acc[i][0]);
                acc[i][0] = fmaf(wA3[i], x1v[0], acc[i][0]);
                acc[i][0] = fmaf(wB1[i], x0v[1], acc[i][0]);
                acc[i][0] = fmaf(wB3[i], x0v[0], acc[i][0]);
                acc[i][1] = fmaf(wA0[i], x1v[2], acc[i][1]);
                acc[i][1] = fmaf(wA2[i], x1v[1], acc[i][1]);
                acc[i][1] = fmaf(wB0[i], x0v[2], acc[i][1]);
                acc[i][1] = fmaf(wB2[i], x0v[1], acc[i][1]);
                acc[i][2] = fmaf(wA1[i], x1v[2], acc[i][2]);
                acc[i][2] = fmaf(wA3[i], x1v[1], acc[i][2]);
                acc[i][2] = fmaf(wB1[i], x0v[2], acc[i][2]);
                acc[i][2] = fmaf(wB3[i], x0v[1], acc[i][2]);
                acc[i][3] = fmaf(wA0[i], x1v[3], acc[i][3]);
                acc[i][3] = fmaf(wA2[i], x1v[2], acc[i][3]);
                acc[i][3] = fmaf(wB0[i], x0v[3], acc[i][3]);
                acc[i][3] = fmaf(wB2[i], x0v[2], acc[i][3]);
            }
        }
        __syncthreads();
    }
#pragma unroll
    for (int i = 0; i < 4; ++i) {
        int oc = oc0 + i;
        float bz = bias[oc];
        float4 vv;
        vv.x = fmaxf(acc[i][0] + bz, 0.f);
        vv.y = fmaxf(acc[i][1] + bz, 0.f);
        vv.z = fmaxf(acc[i][2] + bz, 0.f);
        vv.w = fmaxf(acc[i][3] + bz, 0.f);
        *(float4*)&y[((size_t)(b * 64 + oc) * 64 + oh) * 64 + ow0] = vv;
    }
}

// ---------------------------------------------------------------------------
// h2_cvt: h2 fp32 NCHW (8,64,64,64) -> padded NHWC bf16 hi/lo [8][66][66][64]
// ---------------------------------------------------------------------------
__global__ __launch_bounds__(256) void h2_cvt(
    const float* __restrict__ h2,
    unsigned short* __restrict__ ph, unsigned short* __restrict__ pl)
{
    __shared__ float sX[64 * 65];
    const int bid = blockIdx.x;
    const int b = bid / 66, hp = bid % 66;
    const bool interior = (hp >= 1 && hp <= 64);
    if (interior) {
        for (int i = threadIdx.x; i < 4096; i += 256) {
            int ic = i >> 6, w = i & 63;
            sX[ic * 65 + w] = h2[((size_t)(b * 64 + ic) * 64 + (hp - 1)) * 64 + w];
        }
    }
    __syncthreads();
    const size_t base = ((size_t)(b * 66) + hp) * 66 * 64;
    for (int i = threadIdx.x; i < 4224; i += 256) {
        int wp = i >> 6, ic = i & 63;
        float v = 0.0f;
        if (interior && wp >= 1 && wp <= 64) v = sX[ic * 65 + (wp - 1)];
        unsigned short h = f2bf(v);
        ph[base + i] = h;
        pl[base + i] = f2bf(v - bf2f(h));
    }
}

// ---------------------------------------------------------------------------
// prep_w3: pack dec_w3 (64 in, 156 out, 4, 4) into MFMA B-fragment order.
// ---------------------------------------------------------------------------
__global__ __launch_bounds__(256) void prep_w3(
    const float* __restrict__ w3,
    unsigned short* __restrict__ Bh, unsigned short* __restrict__ Bl)
{
    int id = blockIdx.x * 256 + threadIdx.x;
    if (id >= 20480) return;
    int l = id & 63;
    int nf = (id >> 6) % 10;
    int kk = (id / 640) & 7;
    int c = id / 5120;
    int rh = c >> 1, rw = c & 1;
    int n = nf * 16 + (l & 15);
    int k0 = kk * 32 + (l >> 4) * 8;
    size_t off = (size_t)id * 8;
#pragma unroll
    for (int j = 0; j < 8; ++j) {
        int k = k0 + j;
        int ic = k & 63, tau = k >> 6;
        int dh = tau >> 1, dw = tau & 1;
        int kh = 3 - rh - 2 * dh, kw = 3 - rw - 2 * dw;
        float v = (n < 156) ? w3[((size_t)(ic * 156 + n) * 4 + kh) * 4 + kw] : 0.0f;
        unsigned short h = f2bf(v);
        Bh[off + j] = h;
        Bl[off + j] = f2bf(v - bf2f(h));
    }
}

// ---------------------------------------------------------------------------
// decT3_mfma: convT 64->156 s2 p1 + sigmoid via split-bf16 implicit GEMM.
// ---------------------------------------------------------------------------
__global__ __launch_bounds__(256) void decT3_mfma(
    const unsigned short* __restrict__ ah, const unsigned short* __restrict__ al,
    const unsigned short* __restrict__ Bh, const unsigned short* __restrict__ Bl,
    const float* __restrict__ bias, float* __restrict__ y)
{
    const int bid = blockIdx.x;
    const int b = bid >> 7;
    const int q = (bid >> 1) & 63;
    const int rh = bid & 1;
    const int oh = 2 * q + rh;
    const int t = threadIdx.x;
    const int l = t & 63;
    const int wv = t >> 6;
    const int mh = wv & 1, nh = wv >> 1;
    const int mo = mh * 32;
    const int lr = l & 15;
    const int lk = l >> 4;
    const int icb0 = lk * 8;

    f32x4 acc[2][2][5] = {};

    for (int tau = 0; tau < 4; ++tau) {
        const int dh = tau >> 1, dw = tau & 1;
        const size_t rowbase = ((size_t)(b * 66) + (q + rh + dh)) * 66;
#pragma unroll
        for (int ks = 0; ks < 2; ++ks) {
            const int icb = ks * 32 + icb0;
            bf16x8 Ah[2][2], Al[2][2];
#pragma unroll
            for (int cls = 0; cls < 2; ++cls)
#pragma unroll
                for (int mf = 0; mf < 2; ++mf) {
                    const int p = mo + mf * 16 + lr;
                    const size_t off = (rowbase + (p + cls + dw)) * 64 + icb;
                    Ah[cls][mf] = *(const bf16x8*)(ah + off);
                    Al[cls][mf] = *(const bf16x8*)(al + off);
                }
            const int kk = tau * 2 + ks;
#pragma unroll
            for (int nfl = 0; nfl < 5; ++nfl) {
                const int nf = nh * 5 + nfl;
#pragma unroll
                for (int cls = 0; cls < 2; ++cls) {
                    const int c = rh * 2 + cls;
                    const size_t boff = (((size_t)(c * 8 + kk)) * 10 + nf) * 512 + l * 8;
                    bf16x8 bh = *(const bf16x8*)(Bh + boff);
                    bf16x8 bl = *(const bf16x8*)(Bl + boff);
#pragma unroll
                    for (int mf = 0; mf < 2; ++mf) {
                        acc[cls][mf][nfl] = __builtin_amdgcn_mfma_f32_16x16x32_bf16(Ah[cls][mf], bh, acc[cls][mf][nfl], 0, 0, 0);
                        acc[cls][mf][nfl] = __builtin_amdgcn_mfma_f32_16x16x32_bf16(Ah[cls][mf], bl, acc[cls][mf][nfl], 0, 0, 0);
                        acc[cls][mf][nfl] = __builtin_amdgcn_mfma_f32_16x16x32_bf16(Al[cls][mf], bh, acc[cls][mf][nfl], 0, 0, 0);
                    }
                }
            }
        }
    }

    __shared__ float sC[128 * 81];
#pragma unroll
    for (int pass = 0; pass < 2; ++pass) {
        __syncthreads();
        if (nh == pass) {
#pragma unroll
            for (int cls = 0; cls < 2; ++cls)
#pragma unroll
            for (int mf = 0; mf < 2; ++mf)
#pragma unroll
            for (int nfl = 0; nfl < 5; ++nfl) {
                const int ocl = nfl * 16 + lr;
                const int oc = nh * 80 + ocl;
                const float bz = (oc < 156) ? bias[oc] : 0.0f;
#pragma unroll
                for (int r = 0; r < 4; ++r) {
                    const int p = mo + mf * 16 + lk * 4 + r;
                    const int ow = 2 * p + cls;
                    sC[ow * 81 + ocl] = sigmoidf_(acc[cls][mf][nfl][r] + bz);
                }
            }
        }
        __syncthreads();
        const int ocbase = pass * 80;
        for (int i = t; i < 80 * 128; i += 256) {
            const int ow = i & 127, ocl = i >> 7;
            const int oc = ocbase + ocl;
            if (oc < 156)
                y[(((size_t)(b * 156 + oc)) * 128 + oh) * 128 + ow] = sC[ow * 81 + ocl];
        }
    }
}

// ---------------------------------------------------------------------------
// VQ (unchanged, bit-identical numerics)
// ---------------------------------------------------------------------------
__global__ __launch_bounds__(256) void cb_norms_k(const float* __restrict__ cb,
                                                  float* __restrict__ cbn)
{
    int k = blockIdx.x * 256 + threadIdx.x;
    if (k >= 512) return;
    const float* cp = cb + (size_t)k * 128;
    float s = 0.0f;
#pragma unroll
    for (int d = 0; d < 128; ++d) s = fmaf(cp[d], cp[d], s);
    cbn[k] = s;
}

__global__ __launch_bounds__(256) void vq_k(
    const float* __restrict__ z, const float* __restrict__ cb,
    const float* __restrict__ cbn,
    float* __restrict__ e, float* __restrict__ idxf)
{
    const int blk = blockIdx.x;
    const int b = blk >> 5;
    const int n0 = (blk & 31) << 5;
    const int t = threadIdx.x;
    const int nl = t & 31, kq = t >> 5;
    const int n = n0 + nl;

    float zr[128];
#pragma unroll
    for (int d = 0; d < 128; ++d) zr[d] = z[(size_t)(b * 128 + d) * 1024 + n];
    float zn = 0.0f;
#pragma unroll
    for (int d = 0; d < 128; ++d) zn = fmaf(zr[d], zr[d], zn);

    float best = 3.4e38f;
    int bk = kq * 64;
    for (int k = kq * 64; k < kq * 64 + 64; ++k) {
        const float4* cp = (const float4*)(cb + (size_t)k * 128);
        float dot = 0.0f;
#pragma unroll
        for (int j = 0; j < 32; ++j) {
            float4 c = cp[j];
            dot = fmaf(zr[4 * j + 0], c.x, dot);
            dot = fmaf(zr[4 * j + 1], c.y, dot);
            dot = fmaf(zr[4 * j + 2], c.z, dot);
            dot = fmaf(zr[4 * j + 3], c.w, dot);
        }
        float dist = (zn - 2.0f * dot) + cbn[k];
        if (dist < best) { best = dist; bk = k; }
    }
    __shared__ float sd[8][32];
    __shared__ int si[8][32];
    sd[kq][nl] = best;
    si[kq][nl] = bk;
    __syncthreads();
    if (t < 32) {
#pragma unroll
        for (int q = 1; q < 8; ++q) {
            float d2 = sd[q][nl];
            if (d2 < best) { best = d2; bk = si[q][nl]; }
        }
        si[0][nl] = bk;
        idxf[b * 1024 + n] = (float)bk;
    }
    __syncthreads();
    for (int li = t; li < 4096; li += 256) {
        int d = li >> 5, nn = li & 31;
        e[(size_t)(b * 128 + d) * 1024 + n0 + nn] = cb[(size_t)si[0][nn] * 128 + d];
    }
}

// ---------------------------------------------------------------------------
extern "C" void kernel_launch(void* const* d_in, const int* in_sizes, int n_in,
                              void* d_out, int out_size, void* d_ws, size_t ws_size,
                              hipStream_t stream)
{
    const float* x      = (const float*)d_in[0];
    const float* enc_w1 = (const float*)d_in[1];
    const float* enc_b1 = (const float*)d_in[2];
    const float* bn1_g  = (const float*)d_in[3];
    const float* bn1_b  = (const float*)d_in[4];
    const float* bn1_m  = (const float*)d_in[5];
    const float* bn1_v  = (const float*)d_in[6];
    const float* enc_w2 = (const float*)d_in[7];
    const float* enc_b2 = (const float*)d_in[8];
    const float* bn2_g  = (const float*)d_in[9];
    const float* bn2_b  = (const float*)d_in[10];
    const float* bn2_m  = (const float*)d_in[11];
    const float* bn2_v  = (const float*)d_in[12];
    const float* enc_w3 = (const float*)d_in[13];
    const float* enc_b3 = (const float*)d_in[14];
    const float* cb     = (const float*)d_in[15];
    const float* dec_w1 = (const float*)d_in[16];
    const float* dec_b1 = (const float*)d_in[17];
    const float* dec_w2 = (const float*)d_in[18];
    const float* dec_b2 = (const float*)d_in[19];
    const float* dec_w3 = (const float*)d_in[20];
    const float* dec_b3 = (const float*)d_in[21];

    float* ws = (float*)d_ws;
    float* z1  = ws;                  // (8,64,64,64)   2097152  (dead after conv2)
    float* z2  = z1 + 2097152;        // (8,128,32,32)  1048576  (dead after conv3)
    float* z3  = z2 + 1048576;        // (8,128,32,32)  1048576
    float* cbn = z3 + 1048576;        // (512)
    float* h1  = cbn + 512;           // (8,128,32,32)  1048576
    float* h2  = h1 + 1048576;        // (8,64,64,64)   2097152
    // conv1 weight limbs live in h1's slot (dead until dec conv1 writes it):
    // 3 x 163840 ushorts = 983 KB << 4 MB
    unsigned short* Bw1 = (unsigned short*)h1;
    // h2 padded NHWC bf16 hi/lo overlays z1/z2 (dead by then)
    unsigned short* h2p_hi = (unsigned short*)ws;
    unsigned short* h2p_lo = (unsigned short*)(ws + 1115136);
    unsigned short* B3h = (unsigned short*)(ws + 7340544);
    unsigned short* B3l = (unsigned short*)(ws + 7340544 + 81920);

    float* out   = (float*)d_out;
    float* x_hat = out;               // 20447232
    float* e     = out + 20447232;    // 1048576
    float* idxf  = e + 1048576;       // 8192

    prep_w1<<<80, 256, 0, stream>>>(enc_w1, Bw1);
    prep_w3<<<80, 256, 0, stream>>>(dec_w3, B3h, B3l);
    conv1_mfma<<<512, 256, 0, stream>>>(x, Bw1, enc_b1, bn1_g, bn1_b, bn1_m, bn1_v, z1);
    conv2_k<<<256, 256, 0, stream>>>(z1, enc_w2, enc_b2, bn2_g, bn2_b, bn2_m, bn2_v, z2);
    conv3s1_k<0><<<256, 256, 0, stream>>>(z2, enc_w3, enc_b3, z3);
    cb_norms_k<<<2, 256, 0, stream>>>(cb, cbn);
    vq_k<<<256, 256, 0, stream>>>(z3, cb, cbn, e, idxf);
    conv3s1_k<2><<<256, 256, 0, stream>>>(e, dec_w1, dec_b1, h1);
    decT2_k<<<512, 256, 0, stream>>>(h1, dec_w2, dec_b2, h2);
    h2_cvt<<<528, 256, 0, stream>>>(h2, h2p_hi, h2p_lo);
    decT3_mfma<<<1024, 256, 0, stream>>>(h2p_hi, h2p_lo, B3h, B3l, dec_b3, x_hat);
}